// Round 11
// baseline (1594.817 us; speedup 1.0000x reference)
//
#include <hip/hip_runtime.h>
#include <math.h>

#define NENT 50000
#define NE2 (NENT / 2)
#define NR2 460
#define HD 128
#define TS 8
#define EPC 200000   // edges per step
#define MPC 400000   // r_to_e entries per step
#define RSLOPE 0.22916666666666666f
#define RBLK 128                    // blocks per step for two-level relation CSR build
#define NTOT (TS * NENT)            // 400000 flattened (t, entity)
#define NB8 ((NTOT + 255) / 256)    // 1563 scan blocks
#define SCAN2_PER ((NB8 + 255) / 256)  // 7

typedef __attribute__((ext_vector_type(8))) short bfrag;   // 8 bf16 (4 VGPR)
typedef __attribute__((ext_vector_type(4))) float facc;    // mfma f32x4 acc

__device__ __forceinline__ float sigm(float x) { return 1.0f / (1.0f + expf(-x)); }
__device__ __forceinline__ float rrelu_f(float x) { return x >= 0.0f ? x : RSLOPE * x; }
__device__ __forceinline__ unsigned short f2bf_rne(float x) {
  unsigned u = __float_as_uint(x);
  unsigned r = (u + 0x7FFFu + ((u >> 16) & 1u)) >> 16;
  return (unsigned short)r;
}
__device__ __forceinline__ float bf2f(unsigned short b) {
  return __uint_as_float(((unsigned)b) << 16);
}
__device__ __forceinline__ float bfLO(unsigned u) { return __uint_as_float(u << 16); }
__device__ __forceinline__ float bfHI(unsigned u) { return __uint_as_float(u & 0xFFFF0000u); }
__device__ __forceinline__ unsigned packbf(float x, float y) {
  return (unsigned)f2bf_rne(x) | ((unsigned)f2bf_rne(y) << 16);
}

// ---- row l2 normalize (+ bf16 shadow) ----
__global__ __launch_bounds__(HD) void k_l2rows(const float* __restrict__ in,
                                               float* __restrict__ out,
                                               unsigned short* __restrict__ out_bf) {
  int r = blockIdx.x, j = threadIdx.x;
  __shared__ float red[HD];
  float v = in[(size_t)r * HD + j];
  red[j] = v * v;
  __syncthreads();
  for (int s = HD / 2; s > 0; s >>= 1) { if (j < s) red[j] += red[j + s]; __syncthreads(); }
  float rn = 1.0f / fmaxf(sqrtf(red[0]), 1e-12f);
  float o = v * rn;
  out[(size_t)r * HD + j] = o;
  out_bf[(size_t)r * HD + j] = f2bf_rne(o);
}

// ---- batched histogram ----
__global__ void k_hist(const int* __restrict__ idx, int* __restrict__ cnt,
                       int n, int per_t, int stride) {
  int i = blockIdx.x * blockDim.x + threadIdx.x;
  int gs = gridDim.x * blockDim.x;
  for (; i < n; i += gs) atomicAdd(&cnt[(i / per_t) * stride + idx[i]], 1);
}

// ==== batched two-level relation CSR build ====
__global__ __launch_bounds__(256) void k_histR2(const int* __restrict__ rseg,
                                                int* __restrict__ blkcnt) {
  __shared__ int h[NR2];
  int b = blockIdx.x, t = blockIdx.y, tid = threadIdx.x;
  for (int i = tid; i < NR2; i += 256) h[i] = 0;
  __syncthreads();
  const int* rs = rseg + (size_t)t * MPC;
  int chunk = (MPC + RBLK - 1) / RBLK;
  int m0 = b * chunk, m1 = min(MPC, m0 + chunk);
  for (int m = m0 + tid; m < m1; m += 256) atomicAdd(&h[rs[m]], 1);
  __syncthreads();
  for (int i = tid; i < NR2; i += 256) blkcnt[((size_t)(t * RBLK + b)) * NR2 + i] = h[i];
}

__global__ __launch_bounds__(256) void k_scanR2a(const int* __restrict__ blkcnt,
                                                 int* __restrict__ tot) {
  int idx = blockIdx.x * 256 + threadIdx.x;
  if (idx >= TS * NR2) return;
  int t = idx / NR2, r = idx - t * NR2;
  int s = 0;
  for (int b = 0; b < RBLK; ++b) s += blkcnt[((size_t)(t * RBLK + b)) * NR2 + r];
  tot[idx] = s;
}

__global__ __launch_bounds__(512) void k_scanR2b(const int* __restrict__ tot,
    int* __restrict__ offsR, float* __restrict__ invc) {
  __shared__ int s[TS * NR2];
  int tid = threadIdx.x;
  for (int i = tid; i < TS * NR2; i += 512) s[i] = tot[i];
  __syncthreads();
  if (tid < TS) {
    int acc = tid * MPC;
    for (int r = 0; r < NR2; ++r) { int c = s[tid * NR2 + r]; s[tid * NR2 + r] = acc; acc += c; }
  }
  __syncthreads();
  for (int i = tid; i < TS * NR2; i += 512) {
    offsR[i] = s[i];
    int c = tot[i];
    invc[i] = c > 0 ? 1.0f / (float)c : 0.0f;
  }
  if (tid == 0) offsR[TS * NR2] = TS * MPC;
}

__global__ __launch_bounds__(256) void k_scanR2c(int* __restrict__ blkcnt,
                                                 const int* __restrict__ offsR) {
  int gw = (blockIdx.x * blockDim.x + threadIdx.x) >> 6;
  int lane = threadIdx.x & 63;
  if (gw >= TS * NR2) return;
  int t = gw / NR2, r = gw - t * NR2;
  size_t i0 = ((size_t)(t * RBLK + lane * 2)) * NR2 + r;
  size_t i1 = ((size_t)(t * RBLK + lane * 2 + 1)) * NR2 + r;
  int v0 = blkcnt[i0], v1 = blkcnt[i1];
  int s = v0 + v1;
  int sc = s;
  #pragma unroll
  for (int o = 1; o < 64; o <<= 1) {
    int x = __shfl_up(sc, o, 64);
    if (lane >= o) sc += x;
  }
  int basev = offsR[gw] + (sc - s);
  blkcnt[i0] = basev;
  blkcnt[i1] = basev + v0;
}

__global__ __launch_bounds__(256) void k_scatterR2(const int* __restrict__ rte,
    const int* __restrict__ rseg, const int* __restrict__ blkbase,
    int* __restrict__ out) {
  __shared__ int cur[NR2];
  int b = blockIdx.x, t = blockIdx.y, tid = threadIdx.x;
  for (int i = tid; i < NR2; i += 256) cur[i] = blkbase[((size_t)(t * RBLK + b)) * NR2 + i];
  __syncthreads();
  const int* rs = rseg + (size_t)t * MPC;
  const int* re = rte + (size_t)t * MPC;
  int chunk = (MPC + RBLK - 1) / RBLK;
  int m0 = b * chunk, m1 = min(MPC, m0 + chunk);
  for (int m = m0 + tid; m < m1; m += 256) {
    int r = rs[m];
    int p = atomicAdd(&cur[r], 1);
    out[p] = re[m];
  }
}

// ---- flat 3-phase exclusive scan over TS*NENT degrees ----
__global__ __launch_bounds__(256) void k_scan1(const int* __restrict__ deg,
    int* __restrict__ offs, float* __restrict__ normv, int* __restrict__ bsum) {
  __shared__ int sd[256];
  int b = blockIdx.x, tid = threadIdx.x;
  int i = b * 256 + tid;
  int v = (i < NTOT) ? deg[i] : 0;
  sd[tid] = v;
  __syncthreads();
  for (int o = 1; o < 256; o <<= 1) {
    int x = (tid >= o) ? sd[tid - o] : 0;
    __syncthreads();
    sd[tid] += x;
    __syncthreads();
  }
  if (i < NTOT) {
    offs[i] = sd[tid] - v;
    normv[i] = v > 0 ? 1.0f / (float)v : 0.0f;
  }
  if (tid == 255) bsum[b] = sd[255];
}

__global__ __launch_bounds__(256) void k_scan2(int* __restrict__ bsum) {
  __shared__ int part[256];
  int tid = threadIdx.x;
  int base = tid * SCAN2_PER;
  int local[SCAN2_PER];
  int s = 0;
  #pragma unroll
  for (int k = 0; k < SCAN2_PER; ++k) {
    int v = (base + k < NB8) ? bsum[base + k] : 0;
    local[k] = s;
    s += v;
  }
  part[tid] = s;
  __syncthreads();
  for (int o = 1; o < 256; o <<= 1) {
    int x = (tid >= o) ? part[tid - o] : 0;
    __syncthreads();
    part[tid] += x;
    __syncthreads();
  }
  int pre = (tid > 0) ? part[tid - 1] : 0;
  #pragma unroll
  for (int k = 0; k < SCAN2_PER; ++k)
    if (base + k < NB8) bsum[base + k] = pre + local[k];
}

__global__ __launch_bounds__(256) void k_scan3(int* __restrict__ offs, int* __restrict__ cur,
                                               const int* __restrict__ bsum) {
  int b = blockIdx.x;
  int i = b * 256 + threadIdx.x;
  if (i < NTOT) {
    int o = offs[i] + bsum[b];
    offs[i] = o;
    cur[i] = o;
  }
  if (b == 0 && threadIdx.x == 0) offs[NTOT] = TS * EPC;
}

// packed edge payload: (src << 9) | etype ; t-outer loop keeps write window L2-resident
__global__ void k_scatterE(const int* __restrict__ src, const int* __restrict__ dst,
                           const int* __restrict__ ety, int* __restrict__ cur,
                           unsigned* __restrict__ se) {
  int tid0 = blockIdx.x * blockDim.x + threadIdx.x;
  int gs = gridDim.x * blockDim.x;
  for (int t = 0; t < TS; ++t) {
    const int* s = src + (size_t)t * EPC;
    const int* d = dst + (size_t)t * EPC;
    const int* e = ety + (size_t)t * EPC;
    int* ct = cur + t * NENT;
    for (int i = tid0; i < EPC; i += gs) {
      int dd = d[i];
      int p = atomicAdd(&ct[dd], 1);
      se[p] = ((unsigned)s[i] << 9) | (unsigned)e[i];
    }
  }
}

// ---- W -> fragment-layout bf16 hi/lo (B-operand of mfma_f32_16x16x32_bf16) ----
__global__ __launch_bounds__(256) void k_prepW(const float* __restrict__ W,
    unsigned short* __restrict__ hi, unsigned short* __restrict__ lo) {
  int t = blockIdx.x * 256 + threadIdx.x;   // 0..2047
  int nt = t >> 8, ks = (t >> 6) & 3, lane = t & 63;
  int n = nt * 16 + (lane & 15);
  int k0 = ks * 32 + ((lane >> 4) << 3);
  #pragma unroll
  for (int j = 0; j < 8; ++j) {
    float v = W[(k0 + j) * HD + n];
    unsigned short h = f2bf_rne(v);
    hi[t * 8 + j] = h;
    lo[t * 8 + j] = f2bf_rne(v - bf2f(h));
  }
}

// ---- FUSED relation mean + GRU + l2norm (one block per relation, 8 gather waves) ----
__global__ __launch_bounds__(512) void k_relgru(
    const unsigned short* __restrict__ h_bf,
    const int* __restrict__ offs, const int* __restrict__ rte_csr,
    const float* __restrict__ invcnt,
    const float* __restrict__ emb_rel, const float* __restrict__ h0s,
    const float* __restrict__ Wih, const float* __restrict__ Whh,
    const float* __restrict__ bih, const float* __restrict__ bhh,
    float* __restrict__ h0d, unsigned short* __restrict__ h0d_bf) {
  int rel = blockIdx.x;
  int tid = threadIdx.x;
  int w = __builtin_amdgcn_readfirstlane(tid >> 6);
  int lane = tid & 63;
  int o0 = offs[rel], o1 = offs[rel + 1];
  int n = o1 - o0;
  int s0 = o0 + ((n * w) >> 3);
  int s1 = o0 + ((n * (w + 1)) >> 3);
  const unsigned* h4 = (const unsigned*)h_bf;
  float sx = 0.f, sy = 0.f;
  int p = s0;
  for (; p + 4 <= s1; p += 4) {
    int i0 = rte_csr[p], i1 = rte_csr[p + 1], i2 = rte_csr[p + 2], i3 = rte_csr[p + 3];
    unsigned u0 = h4[(size_t)i0 * 64 + lane];
    unsigned u1 = h4[(size_t)i1 * 64 + lane];
    unsigned u2 = h4[(size_t)i2 * 64 + lane];
    unsigned u3 = h4[(size_t)i3 * 64 + lane];
    sx += (bfLO(u0) + bfLO(u1)) + (bfLO(u2) + bfLO(u3));
    sy += (bfHI(u0) + bfHI(u1)) + (bfHI(u2) + bfHI(u3));
  }
  for (; p < s1; ++p) {
    unsigned u0 = h4[(size_t)rte_csr[p] * 64 + lane];
    sx += bfLO(u0);
    sy += bfHI(u0);
  }
  __shared__ float red[8][HD];
  red[w][lane * 2] = sx;
  red[w][lane * 2 + 1] = sy;
  __syncthreads();
  // ---- GRU on 128 threads ----
  __shared__ __align__(16) float xr[2 * HD];
  __shared__ __align__(16) float hh[HD];
  __shared__ float red2[HD];
  float hv0 = 0.f;
  if (tid < HD) {
    int j = tid;
    float inv = invcnt[rel];
    float xm = 0.f;
    #pragma unroll
    for (int sp = 0; sp < 8; ++sp) xm += red[sp][j];
    xr[j] = emb_rel[rel * HD + j];
    xr[HD + j] = xm * inv;
    hv0 = h0s[rel * HD + j];
    hh[j] = hv0;
  }
  __syncthreads();
  float hv = 0.f;
  if (tid < HD) {
    int j = tid;
    float gr = bih[j], gz = bih[HD + j], gn = bih[2 * HD + j];
    const float4* W4 = (const float4*)Wih;
    int rowA = j * 64, rowB = (j + HD) * 64, rowC = (j + 2 * HD) * 64;
    #pragma unroll 4
    for (int k4 = 0; k4 < 64; ++k4) {
      float4 xa = ((const float4*)xr)[k4];
      float4 w0 = W4[rowA + k4];
      float4 w1 = W4[rowB + k4];
      float4 w2 = W4[rowC + k4];
      gr += w0.x * xa.x + w0.y * xa.y + w0.z * xa.z + w0.w * xa.w;
      gz += w1.x * xa.x + w1.y * xa.y + w1.z * xa.z + w1.w * xa.w;
      gn += w2.x * xa.x + w2.y * xa.y + w2.z * xa.z + w2.w * xa.w;
    }
    float hr = bhh[j], hz = bhh[HD + j], hn = bhh[2 * HD + j];
    const float4* Wh4 = (const float4*)Whh;
    int rA = j * 32, rB = (j + HD) * 32, rC = (j + 2 * HD) * 32;
    #pragma unroll 4
    for (int k4 = 0; k4 < 32; ++k4) {
      float4 xa = ((const float4*)hh)[k4];
      float4 w0 = Wh4[rA + k4];
      float4 w1 = Wh4[rB + k4];
      float4 w2 = Wh4[rC + k4];
      hr += w0.x * xa.x + w0.y * xa.y + w0.z * xa.z + w0.w * xa.w;
      hz += w1.x * xa.x + w1.y * xa.y + w1.z * xa.z + w1.w * xa.w;
      hn += w2.x * xa.x + w2.y * xa.y + w2.z * xa.z + w2.w * xa.w;
    }
    float rg = sigm(gr + hr);
    float zg = sigm(gz + hz);
    float ng = tanhf(gn + rg * hn);
    hv = (1.0f - zg) * ng + zg * hv0;
    red2[tid] = hv * hv;
  }
  __syncthreads();
  for (int s = HD / 2; s > 0; s >>= 1) {
    if (tid < s) red2[tid] += red2[tid + s];
    __syncthreads();
  }
  if (tid < HD) {
    float rn = 1.0f / fmaxf(sqrtf(red2[0]), 1e-12f);
    float o = hv * rn;
    h0d[rel * HD + tid] = o;
    h0d_bf[rel * HD + tid] = f2bf_rne(o);
  }
}

// ---- edge aggregation via dst-CSR: two rows per wave, interleaved MLP ----
// PASS=1: gather nh_bf + h0_bf; agg = (Σnh + Σh0)*nm; Tbf = bf16(Σh0)
// PASS=2: gather nh_bf only;    agg = (Σnh + T)*nm  (T read sequentially)
template<int PASS>
__global__ __launch_bounds__(256) void k_edge2(
    const unsigned short* __restrict__ nh_bf, const unsigned short* __restrict__ h0_bf,
    const int* __restrict__ offs, const unsigned* __restrict__ se,
    const float* __restrict__ norm, unsigned* __restrict__ Tbf,
    float* __restrict__ agg) {
  int gw = __builtin_amdgcn_readfirstlane((blockIdx.x * blockDim.x + threadIdx.x) >> 6);
  int lane = threadIdx.x & 63;
  if (gw >= NE2) return;
  int rA = gw, rB = gw + NE2;
  int a0 = offs[rA], a1 = offs[rA + 1];
  int b0 = offs[rB], b1 = offs[rB + 1];
  const unsigned* nh4 = (const unsigned*)nh_bf;
  const unsigned* h04 = (const unsigned*)h0_bf;
  float nax = 0.f, nay = 0.f, tax = 0.f, tay = 0.f;
  float nbx = 0.f, nby = 0.f, tbx = 0.f, tby = 0.f;
  int pa = a0, pb = b0;
  for (; pa + 4 <= a1 && pb + 4 <= b1; pa += 4, pb += 4) {
    unsigned e0 = se[pa], e1 = se[pa + 1], e2 = se[pa + 2], e3 = se[pa + 3];
    unsigned f0 = se[pb], f1 = se[pb + 1], f2 = se[pb + 2], f3 = se[pb + 3];
    unsigned ua = nh4[(size_t)(e0 >> 9) * 64 + lane];
    unsigned ub = nh4[(size_t)(e1 >> 9) * 64 + lane];
    unsigned uc = nh4[(size_t)(e2 >> 9) * 64 + lane];
    unsigned ud = nh4[(size_t)(e3 >> 9) * 64 + lane];
    unsigned va = nh4[(size_t)(f0 >> 9) * 64 + lane];
    unsigned vb = nh4[(size_t)(f1 >> 9) * 64 + lane];
    unsigned vc = nh4[(size_t)(f2 >> 9) * 64 + lane];
    unsigned vd = nh4[(size_t)(f3 >> 9) * 64 + lane];
    nax += (bfLO(ua) + bfLO(ub)) + (bfLO(uc) + bfLO(ud));
    nay += (bfHI(ua) + bfHI(ub)) + (bfHI(uc) + bfHI(ud));
    nbx += (bfLO(va) + bfLO(vb)) + (bfLO(vc) + bfLO(vd));
    nby += (bfHI(va) + bfHI(vb)) + (bfHI(vc) + bfHI(vd));
    if (PASS == 1) {
      unsigned ha = h04[(size_t)(e0 & 511u) * 64 + lane];
      unsigned hb = h04[(size_t)(e1 & 511u) * 64 + lane];
      unsigned hc = h04[(size_t)(e2 & 511u) * 64 + lane];
      unsigned hd = h04[(size_t)(e3 & 511u) * 64 + lane];
      unsigned ga = h04[(size_t)(f0 & 511u) * 64 + lane];
      unsigned gb = h04[(size_t)(f1 & 511u) * 64 + lane];
      unsigned gc = h04[(size_t)(f2 & 511u) * 64 + lane];
      unsigned gd = h04[(size_t)(f3 & 511u) * 64 + lane];
      tax += (bfLO(ha) + bfLO(hb)) + (bfLO(hc) + bfLO(hd));
      tay += (bfHI(ha) + bfHI(hb)) + (bfHI(hc) + bfHI(hd));
      tbx += (bfLO(ga) + bfLO(gb)) + (bfLO(gc) + bfLO(gd));
      tby += (bfHI(ga) + bfHI(gb)) + (bfHI(gc) + bfHI(gd));
    }
  }
  for (; pa < a1; ++pa) {
    unsigned e0 = se[pa];
    unsigned ua = nh4[(size_t)(e0 >> 9) * 64 + lane];
    nax += bfLO(ua);
    nay += bfHI(ua);
    if (PASS == 1) {
      unsigned ha = h04[(size_t)(e0 & 511u) * 64 + lane];
      tax += bfLO(ha);
      tay += bfHI(ha);
    }
  }
  for (; pb < b1; ++pb) {
    unsigned f0 = se[pb];
    unsigned va = nh4[(size_t)(f0 >> 9) * 64 + lane];
    nbx += bfLO(va);
    nby += bfHI(va);
    if (PASS == 1) {
      unsigned ga = h04[(size_t)(f0 & 511u) * 64 + lane];
      tbx += bfLO(ga);
      tby += bfHI(ga);
    }
  }
  float nma = norm[rA], nmb = norm[rB];
  if (PASS == 1) {
    Tbf[(size_t)rA * 64 + lane] = packbf(tax, tay);
    Tbf[(size_t)rB * 64 + lane] = packbf(tbx, tby);
    ((float2*)agg)[(size_t)rA * 64 + lane] = make_float2((nax + tax) * nma, (nay + tay) * nma);
    ((float2*)agg)[(size_t)rB * 64 + lane] = make_float2((nbx + tbx) * nmb, (nby + tby) * nmb);
  } else {
    unsigned tva = Tbf[(size_t)rA * 64 + lane];
    unsigned tvb = Tbf[(size_t)rB * 64 + lane];
    ((float2*)agg)[(size_t)rA * 64 + lane] =
        make_float2((nax + bfLO(tva)) * nma, (nay + bfHI(tva)) * nma);
    ((float2*)agg)[(size_t)rB * 64 + lane] =
        make_float2((nbx + bfLO(tvb)) * nmb, (nby + bfHI(tvb)) * nmb);
  }
}

// ---- stage helper: fp32 global rows -> swizzled hi/lo bf16 LDS ----
__device__ __forceinline__ void stage_rows(const float* __restrict__ A, int base, int nrows,
                                           unsigned short* AsH, unsigned short* AsL,
                                           int tid) {
  const float4* A4 = (const float4*)A;
  #pragma unroll
  for (int it = 0; it < 8; ++it) {
    int idx = tid + it * 256;          // 0..2047
    int r = idx >> 5, c4 = idx & 31;
    int c0 = c4 * 4;
    float4 v = make_float4(0.f, 0.f, 0.f, 0.f);
    if (base + r < nrows) v = A4[(size_t)(base + r) * 32 + c4];
    int chunk = (c0 >> 3) ^ (r & 7);
    int p = r * 128 + chunk * 8 + (c0 & 7);
    unsigned short h0 = f2bf_rne(v.x), h1 = f2bf_rne(v.y);
    unsigned short h2 = f2bf_rne(v.z), h3 = f2bf_rne(v.w);
    ushort4 hv; hv.x = h0; hv.y = h1; hv.z = h2; hv.w = h3;
    *(ushort4*)&AsH[p] = hv;
    ushort4 lv;
    lv.x = f2bf_rne(v.x - bf2f(h0)); lv.y = f2bf_rne(v.y - bf2f(h1));
    lv.z = f2bf_rne(v.z - bf2f(h2)); lv.w = f2bf_rne(v.w - bf2f(h3));
    *(ushort4*)&AsL[p] = lv;
  }
}

// ---- MFMA split-bf16 core: acc += As @ Wfrag ----
__device__ __forceinline__ void mfma_128(const unsigned short* AsH, const unsigned short* AsL,
                                         const unsigned short* __restrict__ wHi,
                                         const unsigned short* __restrict__ wLo,
                                         int w, int lane, facc* acc) {
  int lrow = lane & 15;
  int arow = w * 16 + lrow;
  #pragma unroll
  for (int ks = 0; ks < 4; ++ks) {
    int chunk = (ks * 4 + (lane >> 4)) ^ (arow & 7);
    int p = arow * 128 + chunk * 8;
    bfrag aH = *(const bfrag*)&AsH[p];
    bfrag aL = *(const bfrag*)&AsL[p];
    #pragma unroll
    for (int nt = 0; nt < 8; ++nt) {
      int fi = ((nt * 4 + ks) * 64 + lane) * 8;
      bfrag bH = *(const bfrag*)&wHi[fi];
      bfrag bL = *(const bfrag*)&wLo[fi];
      acc[nt] = __builtin_amdgcn_mfma_f32_16x16x32_bf16(aH, bH, acc[nt], 0, 0, 0);
      acc[nt] = __builtin_amdgcn_mfma_f32_16x16x32_bf16(aH, bL, acc[nt], 0, 0, 0);
      acc[nt] = __builtin_amdgcn_mfma_f32_16x16x32_bf16(aL, bH, acc[nt], 0, 0, 0);
    }
  }
}

// ---- layer-1 matmul: agg1 (fp32) -> agg1_bf = bf16(rrelu(agg1 @ W1)) ----
__global__ __launch_bounds__(256) void k_mm1(
    const float* __restrict__ A, unsigned short* __restrict__ Abf,
    const unsigned short* __restrict__ wHi, const unsigned short* __restrict__ wLo,
    int nrows) {
  __shared__ __align__(16) unsigned short AsH[64 * 128];
  __shared__ __align__(16) unsigned short AsL[64 * 128];
  int tid = threadIdx.x;
  int base = blockIdx.x * 64;
  stage_rows(A, base, nrows, AsH, AsL, tid);
  __syncthreads();
  int w = tid >> 6, lane = tid & 63;
  int lrow = lane & 15, lk = lane >> 4;
  facc acc[8];
  #pragma unroll
  for (int nt = 0; nt < 8; ++nt) acc[nt] = (facc){0.f, 0.f, 0.f, 0.f};
  mfma_128(AsH, AsL, wHi, wLo, w, lane, acc);
  #pragma unroll
  for (int nt = 0; nt < 8; ++nt)
    #pragma unroll
    for (int r = 0; r < 4; ++r) {
      int row = base + w * 16 + lk * 4 + r;
      if (row < nrows) Abf[(size_t)row * HD + nt * 16 + lrow] = f2bf_rne(rrelu_f(acc[nt][r]));
    }
}

// ---- FUSED layer-2 matmul + time-gate final ----
__global__ __launch_bounds__(256) void k_mm2_final(
    const float* __restrict__ A, const float* __restrict__ Hin,
    float* __restrict__ Hout, unsigned short* __restrict__ Hout_bf,
    const unsigned short* __restrict__ w2Hi, const unsigned short* __restrict__ w2Lo,
    const unsigned short* __restrict__ wtHi, const unsigned short* __restrict__ wtLo,
    const float* __restrict__ bias, int nrows) {
  __shared__ __align__(16) unsigned short AsH[64 * 128];
  __shared__ __align__(16) unsigned short AsL[64 * 128];
  int tid = threadIdx.x;
  int base = blockIdx.x * 64;
  int w = tid >> 6, lane = tid & 63;
  int lrow = lane & 15, lk = lane >> 4;
  // phase 1: C = rrelu(agg2 @ W2)
  stage_rows(A, base, nrows, AsH, AsL, tid);
  __syncthreads();
  facc acc[8];
  #pragma unroll
  for (int nt = 0; nt < 8; ++nt) acc[nt] = (facc){0.f, 0.f, 0.f, 0.f};
  mfma_128(AsH, AsL, w2Hi, w2Lo, w, lane, acc);
  #pragma unroll
  for (int nt = 0; nt < 8; ++nt)
    #pragma unroll
    for (int r = 0; r < 4; ++r) acc[nt][r] = rrelu_f(acc[nt][r]);
  __syncthreads();   // all LDS reads of phase 1 done before overwrite
  // phase 2: tw-gate matmul on Hin
  stage_rows(Hin, base, nrows, AsH, AsL, tid);
  __syncthreads();
  facc acc2[8];
  #pragma unroll
  for (int nt = 0; nt < 8; ++nt) acc2[nt] = (facc){0.f, 0.f, 0.f, 0.f};
  mfma_128(AsH, AsL, wtHi, wtLo, w, lane, acc2);
  // l2norm of C rows (one wave owns a full row: 16 lanes x 8 nt)
  float ss[4] = {0.f, 0.f, 0.f, 0.f};
  #pragma unroll
  for (int r = 0; r < 4; ++r) {
    #pragma unroll
    for (int nt = 0; nt < 8; ++nt) ss[r] += acc[nt][r] * acc[nt][r];
    #pragma unroll
    for (int o = 1; o < 16; o <<= 1) ss[r] += __shfl_xor(ss[r], o, 64);
    ss[r] = 1.0f / fmaxf(sqrtf(ss[r]), 1e-12f);
  }
  #pragma unroll
  for (int r = 0; r < 4; ++r) {
    int row = base + w * 16 + lk * 4 + r;
    if (row >= nrows) continue;
    #pragma unroll
    for (int nt = 0; nt < 8; ++nt) {
      int col = nt * 16 + lrow;
      float hv = Hin[(size_t)row * HD + col];
      float tw = sigm(acc2[nt][r] + bias[col]);
      float res = tw * (acc[nt][r] * ss[r]) + (1.0f - tw) * hv;
      Hout[(size_t)row * HD + col] = res;
      Hout_bf[(size_t)row * HD + col] = f2bf_rne(res);
    }
  }
}

extern "C" void kernel_launch(void* const* d_in, const int* in_sizes, int n_in,
                              void* d_out, int out_size, void* d_ws, size_t ws_size,
                              hipStream_t stream) {
  const int* src    = (const int*)d_in[0];
  const int* dst    = (const int*)d_in[1];
  const int* etype  = (const int*)d_in[2];
  const int* rte    = (const int*)d_in[3];
  const int* rseg   = (const int*)d_in[4];
  const float* dyn  = (const float*)d_in[5];
  const float* emb_rel = (const float*)d_in[6];
  const float* W_ih = (const float*)d_in[7];
  const float* W_hh = (const float*)d_in[8];
  const float* b_ih = (const float*)d_in[9];
  const float* b_hh = (const float*)d_in[10];
  const float* rgcnW = (const float*)d_in[11];
  const float* tgW  = (const float*)d_in[12];
  const float* tgB  = (const float*)d_in[13];
  float* out = (float*)d_out;
  (void)in_sizes; (void)n_in; (void)out_size; (void)ws_size;

  float* ws = (float*)d_ws;
  size_t off = 0;
  float* agg1    = ws + off; off += (size_t)NENT * HD;
  float* agg2    = ws + off; off += (size_t)NENT * HD;
  float* h0a     = ws + off; off += (size_t)NR2 * HD;
  float* h0b     = ws + off; off += (size_t)NR2 * HD;
  float* normv8  = ws + off; off += NTOT;
  float* invc8   = ws + off; off += TS * NR2;
  off = (off + 3) & ~(size_t)3;
  unsigned* Tbf  = (unsigned*)(ws + off); off += (size_t)NENT * 64;
  unsigned short* h_bf    = (unsigned short*)(ws + off); off += (size_t)NENT * HD / 2;
  unsigned short* agg1_bf = (unsigned short*)(ws + off); off += (size_t)NENT * HD / 2;
  unsigned short* h0abf   = (unsigned short*)(ws + off); off += (size_t)NR2 * HD / 2 + 1;
  unsigned short* h0bbf   = (unsigned short*)(ws + off); off += (size_t)NR2 * HD / 2 + 1;
  unsigned short* wf = (unsigned short*)(ws + off);
  unsigned short* w1H = wf;            unsigned short* w1L = wf + 16384;
  unsigned short* w2H = wf + 32768;    unsigned short* w2L = wf + 49152;
  unsigned short* wtH = wf + 65536;    unsigned short* wtL = wf + 81920;
  off += (6 * 16384) / 2;
  unsigned* csr_se8 = (unsigned*)(ws + off); off += (size_t)TS * EPC;
  int* csr_rte8  = (int*)(ws + off);  off += (size_t)TS * MPC;
  int* degE8     = (int*)(ws + off);  off += NTOT;
  int* offsE8    = (int*)(ws + off);  off += NTOT + 2;
  int* curE8     = (int*)(ws + off);  off += NTOT;
  int* bsum      = (int*)(ws + off);  off += NB8;
  int* blkcntR8  = (int*)(ws + off);  off += (size_t)TS * RBLK * NR2;
  int* offsR8    = (int*)(ws + off);  off += TS * NR2 + 2;
  int* totR      = (int*)(ws + off);  off += TS * NR2;

  // ===== hoisted, batched CSR builds for all TS steps (input-only) =====
  hipMemsetAsync(degE8, 0, (size_t)NTOT * sizeof(int), stream);
  k_hist<<<2048, 256, 0, stream>>>(dst, degE8, TS * EPC, EPC, NENT);
  k_scan1<<<NB8, 256, 0, stream>>>(degE8, offsE8, normv8, bsum);
  k_scan2<<<1, 256, 0, stream>>>(bsum);
  k_scan3<<<NB8, 256, 0, stream>>>(offsE8, curE8, bsum);
  k_scatterE<<<1024, 256, 0, stream>>>(src, dst, etype, curE8, csr_se8);
  k_histR2<<<dim3(RBLK, TS), 256, 0, stream>>>(rseg, blkcntR8);
  k_scanR2a<<<(TS * NR2 + 255) / 256, 256, 0, stream>>>(blkcntR8, totR);
  k_scanR2b<<<1, 512, 0, stream>>>(totR, offsR8, invc8);
  k_scanR2c<<<(TS * NR2 * 64 + 255) / 256, 256, 0, stream>>>(blkcntR8, offsR8);
  k_scatterR2<<<dim3(RBLK, TS), 256, 0, stream>>>(rte, rseg, blkcntR8, csr_rte8);
  k_prepW<<<8, 256, 0, stream>>>(rgcnW, w1H, w1L);
  k_prepW<<<8, 256, 0, stream>>>(rgcnW + HD * HD, w2H, w2L);
  k_prepW<<<8, 256, 0, stream>>>(tgW, wtH, wtL);

  // h_init = l2norm(dynamic_emb) -> d_out slot 0 + bf16 shadow
  k_l2rows<<<NENT, HD, 0, stream>>>(dyn, out, h_bf);

  float* h0bufs[2] = {h0a, h0b};
  unsigned short* h0bfbufs[2] = {h0abf, h0bbf};
  for (int t = 0; t < TS; ++t) {
    const float* h = out + (size_t)(t == 0 ? 0 : (t - 1)) * NENT * HD;
    float* hout = out + (size_t)t * NENT * HD;
    const float* h0s = (t == 0) ? emb_rel : h0bufs[(t - 1) & 1];
    float* h0d = h0bufs[t & 1];
    unsigned short* h0d_bf = h0bfbufs[t & 1];

    k_relgru<<<NR2, 512, 0, stream>>>(h_bf, offsR8 + t * NR2, csr_rte8,
                                      invc8 + t * NR2, emb_rel, h0s,
                                      W_ih, W_hh, b_ih, b_hh, h0d, h0d_bf);

    k_edge2<1><<<(NE2 * 64 + 255) / 256, 256, 0, stream>>>(
        h_bf, h0d_bf, offsE8 + t * NENT, csr_se8, normv8 + t * NENT, Tbf, agg1);
    k_mm1<<<(NENT + 63) / 64, 256, 0, stream>>>(agg1, agg1_bf, w1H, w1L, NENT);
    k_edge2<2><<<(NE2 * 64 + 255) / 256, 256, 0, stream>>>(
        agg1_bf, (const unsigned short*)nullptr, offsE8 + t * NENT, csr_se8,
        normv8 + t * NENT, Tbf, agg2);
    k_mm2_final<<<(NENT + 63) / 64, 256, 0, stream>>>(agg2, h, hout, h_bf,
                                                      w2H, w2L, wtH, wtL, tgB, NENT);
  }
  hipMemcpyAsync(out + (size_t)TS * NENT * HD, h0bufs[(TS - 1) & 1],
                 (size_t)NR2 * HD * sizeof(float), hipMemcpyDeviceToDevice, stream);
}

// Round 12
// 1589.073 us; speedup vs baseline: 1.0036x; 1.0036x over previous
//
#include <hip/hip_runtime.h>
#include <math.h>

#define NENT 50000
#define NE2 (NENT / 2)
#define NR2 460
#define HD 128
#define TS 8
#define EPC 200000   // edges per step
#define MPC 400000   // r_to_e entries per step
#define RSLOPE 0.22916666666666666f
#define RBLK 128                    // blocks per step for two-level relation CSR build
#define NTOT (TS * NENT)            // 400000 flattened (t, entity)
#define NB8 ((NTOT + 255) / 256)    // 1563 scan blocks
#define SCAN2_PER ((NB8 + 255) / 256)  // 7
#define RSP 8                       // relmean splits

typedef __attribute__((ext_vector_type(8))) short bfrag;   // 8 bf16 (4 VGPR)
typedef __attribute__((ext_vector_type(4))) float facc;    // mfma f32x4 acc

__device__ __forceinline__ float sigm(float x) { return 1.0f / (1.0f + expf(-x)); }
__device__ __forceinline__ float rrelu_f(float x) { return x >= 0.0f ? x : RSLOPE * x; }
__device__ __forceinline__ unsigned short f2bf_rne(float x) {
  unsigned u = __float_as_uint(x);
  unsigned r = (u + 0x7FFFu + ((u >> 16) & 1u)) >> 16;
  return (unsigned short)r;
}
__device__ __forceinline__ float bf2f(unsigned short b) {
  return __uint_as_float(((unsigned)b) << 16);
}
__device__ __forceinline__ float bfLO(unsigned u) { return __uint_as_float(u << 16); }
__device__ __forceinline__ float bfHI(unsigned u) { return __uint_as_float(u & 0xFFFF0000u); }
__device__ __forceinline__ unsigned packbf(float x, float y) {
  return (unsigned)f2bf_rne(x) | ((unsigned)f2bf_rne(y) << 16);
}

// ---- row l2 normalize (+ bf16 shadow) ----
__global__ __launch_bounds__(HD) void k_l2rows(const float* __restrict__ in,
                                               float* __restrict__ out,
                                               unsigned short* __restrict__ out_bf) {
  int r = blockIdx.x, j = threadIdx.x;
  __shared__ float red[HD];
  float v = in[(size_t)r * HD + j];
  red[j] = v * v;
  __syncthreads();
  for (int s = HD / 2; s > 0; s >>= 1) { if (j < s) red[j] += red[j + s]; __syncthreads(); }
  float rn = 1.0f / fmaxf(sqrtf(red[0]), 1e-12f);
  float o = v * rn;
  out[(size_t)r * HD + j] = o;
  out_bf[(size_t)r * HD + j] = f2bf_rne(o);
}

// ---- batched histogram ----
__global__ void k_hist(const int* __restrict__ idx, int* __restrict__ cnt,
                       int n, int per_t, int stride) {
  int i = blockIdx.x * blockDim.x + threadIdx.x;
  int gs = gridDim.x * blockDim.x;
  for (; i < n; i += gs) atomicAdd(&cnt[(i / per_t) * stride + idx[i]], 1);
}

// ==== batched two-level relation CSR build ====
__global__ __launch_bounds__(256) void k_histR2(const int* __restrict__ rseg,
                                                int* __restrict__ blkcnt) {
  __shared__ int h[NR2];
  int b = blockIdx.x, t = blockIdx.y, tid = threadIdx.x;
  for (int i = tid; i < NR2; i += 256) h[i] = 0;
  __syncthreads();
  const int* rs = rseg + (size_t)t * MPC;
  int chunk = (MPC + RBLK - 1) / RBLK;
  int m0 = b * chunk, m1 = min(MPC, m0 + chunk);
  for (int m = m0 + tid; m < m1; m += 256) atomicAdd(&h[rs[m]], 1);
  __syncthreads();
  for (int i = tid; i < NR2; i += 256) blkcnt[((size_t)(t * RBLK + b)) * NR2 + i] = h[i];
}

__global__ __launch_bounds__(256) void k_scanR2a(const int* __restrict__ blkcnt,
                                                 int* __restrict__ tot) {
  int idx = blockIdx.x * 256 + threadIdx.x;
  if (idx >= TS * NR2) return;
  int t = idx / NR2, r = idx - t * NR2;
  int s = 0;
  for (int b = 0; b < RBLK; ++b) s += blkcnt[((size_t)(t * RBLK + b)) * NR2 + r];
  tot[idx] = s;
}

__global__ __launch_bounds__(512) void k_scanR2b(const int* __restrict__ tot,
    int* __restrict__ offsR, float* __restrict__ invc) {
  __shared__ int s[TS * NR2];
  int tid = threadIdx.x;
  for (int i = tid; i < TS * NR2; i += 512) s[i] = tot[i];
  __syncthreads();
  if (tid < TS) {
    int acc = tid * MPC;
    for (int r = 0; r < NR2; ++r) { int c = s[tid * NR2 + r]; s[tid * NR2 + r] = acc; acc += c; }
  }
  __syncthreads();
  for (int i = tid; i < TS * NR2; i += 512) {
    offsR[i] = s[i];
    int c = tot[i];
    invc[i] = c > 0 ? 1.0f / (float)c : 0.0f;
  }
  if (tid == 0) offsR[TS * NR2] = TS * MPC;
}

__global__ __launch_bounds__(256) void k_scanR2c(int* __restrict__ blkcnt,
                                                 const int* __restrict__ offsR) {
  int gw = (blockIdx.x * blockDim.x + threadIdx.x) >> 6;
  int lane = threadIdx.x & 63;
  if (gw >= TS * NR2) return;
  int t = gw / NR2, r = gw - t * NR2;
  size_t i0 = ((size_t)(t * RBLK + lane * 2)) * NR2 + r;
  size_t i1 = ((size_t)(t * RBLK + lane * 2 + 1)) * NR2 + r;
  int v0 = blkcnt[i0], v1 = blkcnt[i1];
  int s = v0 + v1;
  int sc = s;
  #pragma unroll
  for (int o = 1; o < 64; o <<= 1) {
    int x = __shfl_up(sc, o, 64);
    if (lane >= o) sc += x;
  }
  int basev = offsR[gw] + (sc - s);
  blkcnt[i0] = basev;
  blkcnt[i1] = basev + v0;
}

__global__ __launch_bounds__(256) void k_scatterR2(const int* __restrict__ rte,
    const int* __restrict__ rseg, const int* __restrict__ blkbase,
    int* __restrict__ out) {
  __shared__ int cur[NR2];
  int b = blockIdx.x, t = blockIdx.y, tid = threadIdx.x;
  for (int i = tid; i < NR2; i += 256) cur[i] = blkbase[((size_t)(t * RBLK + b)) * NR2 + i];
  __syncthreads();
  const int* rs = rseg + (size_t)t * MPC;
  const int* re = rte + (size_t)t * MPC;
  int chunk = (MPC + RBLK - 1) / RBLK;
  int m0 = b * chunk, m1 = min(MPC, m0 + chunk);
  for (int m = m0 + tid; m < m1; m += 256) {
    int r = rs[m];
    int p = atomicAdd(&cur[r], 1);
    out[p] = re[m];
  }
}

// ---- flat 3-phase exclusive scan over TS*NENT degrees ----
__global__ __launch_bounds__(256) void k_scan1(const int* __restrict__ deg,
    int* __restrict__ offs, float* __restrict__ normv, int* __restrict__ bsum) {
  __shared__ int sd[256];
  int b = blockIdx.x, tid = threadIdx.x;
  int i = b * 256 + tid;
  int v = (i < NTOT) ? deg[i] : 0;
  sd[tid] = v;
  __syncthreads();
  for (int o = 1; o < 256; o <<= 1) {
    int x = (tid >= o) ? sd[tid - o] : 0;
    __syncthreads();
    sd[tid] += x;
    __syncthreads();
  }
  if (i < NTOT) {
    offs[i] = sd[tid] - v;
    normv[i] = v > 0 ? 1.0f / (float)v : 0.0f;
  }
  if (tid == 255) bsum[b] = sd[255];
}

__global__ __launch_bounds__(256) void k_scan2(int* __restrict__ bsum) {
  __shared__ int part[256];
  int tid = threadIdx.x;
  int base = tid * SCAN2_PER;
  int local[SCAN2_PER];
  int s = 0;
  #pragma unroll
  for (int k = 0; k < SCAN2_PER; ++k) {
    int v = (base + k < NB8) ? bsum[base + k] : 0;
    local[k] = s;
    s += v;
  }
  part[tid] = s;
  __syncthreads();
  for (int o = 1; o < 256; o <<= 1) {
    int x = (tid >= o) ? part[tid - o] : 0;
    __syncthreads();
    part[tid] += x;
    __syncthreads();
  }
  int pre = (tid > 0) ? part[tid - 1] : 0;
  #pragma unroll
  for (int k = 0; k < SCAN2_PER; ++k)
    if (base + k < NB8) bsum[base + k] = pre + local[k];
}

__global__ __launch_bounds__(256) void k_scan3(int* __restrict__ offs, int* __restrict__ cur,
                                               const int* __restrict__ bsum) {
  int b = blockIdx.x;
  int i = b * 256 + threadIdx.x;
  if (i < NTOT) {
    int o = offs[i] + bsum[b];
    offs[i] = o;
    cur[i] = o;
  }
  if (b == 0 && threadIdx.x == 0) offs[NTOT] = TS * EPC;
}

// packed edge payload: (src << 9) | etype ; t-outer loop keeps write window L2-resident
__global__ void k_scatterE(const int* __restrict__ src, const int* __restrict__ dst,
                           const int* __restrict__ ety, int* __restrict__ cur,
                           unsigned* __restrict__ se) {
  int tid0 = blockIdx.x * blockDim.x + threadIdx.x;
  int gs = gridDim.x * blockDim.x;
  for (int t = 0; t < TS; ++t) {
    const int* s = src + (size_t)t * EPC;
    const int* d = dst + (size_t)t * EPC;
    const int* e = ety + (size_t)t * EPC;
    int* ct = cur + t * NENT;
    for (int i = tid0; i < EPC; i += gs) {
      int dd = d[i];
      int p = atomicAdd(&ct[dd], 1);
      se[p] = ((unsigned)s[i] << 9) | (unsigned)e[i];
    }
  }
}

// ---- W -> fragment-layout bf16 hi/lo (B-operand of mfma_f32_16x16x32_bf16) ----
__global__ __launch_bounds__(256) void k_prepW(const float* __restrict__ W,
    unsigned short* __restrict__ hi, unsigned short* __restrict__ lo) {
  int t = blockIdx.x * 256 + threadIdx.x;   // 0..2047
  int nt = t >> 8, ks = (t >> 6) & 3, lane = t & 63;
  int n = nt * 16 + (lane & 15);
  int k0 = ks * 32 + ((lane >> 4) << 3);
  #pragma unroll
  for (int j = 0; j < 8; ++j) {
    float v = W[(k0 + j) * HD + n];
    unsigned short h = f2bf_rne(v);
    hi[t * 8 + j] = h;
    lo[t * 8 + j] = f2bf_rne(v - bf2f(h));
  }
}

// ---- relation partial sums via CSR gather (bf16 rows, 4-deep MLP, 460x8 blocks) ----
__global__ __launch_bounds__(256) void k_relmean(const unsigned short* __restrict__ h_bf,
    const int* __restrict__ offs, const int* __restrict__ rte_csr,
    float* __restrict__ partials) {
  int rel = blockIdx.x, sp = blockIdx.y;
  int o0 = offs[rel], o1 = offs[rel + 1];
  int n = o1 - o0;
  int w = __builtin_amdgcn_readfirstlane(threadIdx.x >> 6);
  int lane = threadIdx.x & 63;
  int s0 = o0 + ((n * sp) >> 3);
  int s1 = o0 + ((n * (sp + 1)) >> 3);
  const unsigned* h4 = (const unsigned*)h_bf;   // 2 bf16 per u32; row = 64 u32
  float sx = 0.f, sy = 0.f;
  int p = s0 + w;
  for (; p + 12 < s1; p += 16) {   // 4-deep MLP, wave-stride 4
    int i0 = rte_csr[p];
    int i1 = rte_csr[p + 4];
    int i2 = rte_csr[p + 8];
    int i3 = rte_csr[p + 12];
    unsigned u0 = h4[(size_t)i0 * 64 + lane];
    unsigned u1 = h4[(size_t)i1 * 64 + lane];
    unsigned u2 = h4[(size_t)i2 * 64 + lane];
    unsigned u3 = h4[(size_t)i3 * 64 + lane];
    sx += (bfLO(u0) + bfLO(u1)) + (bfLO(u2) + bfLO(u3));
    sy += (bfHI(u0) + bfHI(u1)) + (bfHI(u2) + bfHI(u3));
  }
  for (; p < s1; p += 4) {
    unsigned u0 = h4[(size_t)rte_csr[p] * 64 + lane];
    sx += bfLO(u0);
    sy += bfHI(u0);
  }
  __shared__ float red[4][HD];
  red[w][lane * 2] = sx;
  red[w][lane * 2 + 1] = sy;
  __syncthreads();
  if (threadIdx.x < HD) {
    int j = threadIdx.x;
    float t = red[0][j] + red[1][j] + red[2][j] + red[3][j];
    partials[((size_t)sp * NR2 + rel) * HD + j] = t;
  }
}

// ---- GRU cell + l2norm for 460 relation rows (+ bf16 shadow) ----
__global__ __launch_bounds__(HD) void k_gru(
    const float* __restrict__ partials, const float* __restrict__ invcnt,
    const float* __restrict__ emb_rel, const float* __restrict__ h0s,
    const float* __restrict__ Wih, const float* __restrict__ Whh,
    const float* __restrict__ bih, const float* __restrict__ bhh,
    float* __restrict__ h0d, unsigned short* __restrict__ h0d_bf) {
  int r = blockIdx.x, j = threadIdx.x;
  __shared__ __align__(16) float xr[2 * HD];
  __shared__ __align__(16) float hh[HD];
  __shared__ float red[HD];
  float inv = invcnt[r];
  xr[j] = emb_rel[r * HD + j];
  float xm = 0.f;
  #pragma unroll
  for (int sp = 0; sp < RSP; ++sp) xm += partials[((size_t)sp * NR2 + r) * HD + j];
  xr[HD + j] = xm * inv;
  float hv0 = h0s[r * HD + j];
  hh[j] = hv0;
  __syncthreads();
  float gr = bih[j], gz = bih[HD + j], gn = bih[2 * HD + j];
  const float4* W4 = (const float4*)Wih;
  int rowA = j * 64, rowB = (j + HD) * 64, rowC = (j + 2 * HD) * 64;
  #pragma unroll 4
  for (int k4 = 0; k4 < 64; ++k4) {
    float4 xa = ((const float4*)xr)[k4];
    float4 w0 = W4[rowA + k4];
    float4 w1 = W4[rowB + k4];
    float4 w2 = W4[rowC + k4];
    gr += w0.x * xa.x + w0.y * xa.y + w0.z * xa.z + w0.w * xa.w;
    gz += w1.x * xa.x + w1.y * xa.y + w1.z * xa.z + w1.w * xa.w;
    gn += w2.x * xa.x + w2.y * xa.y + w2.z * xa.z + w2.w * xa.w;
  }
  float hr = bhh[j], hz = bhh[HD + j], hn = bhh[2 * HD + j];
  const float4* Wh4 = (const float4*)Whh;
  int rA = j * 32, rB = (j + HD) * 32, rC = (j + 2 * HD) * 32;
  #pragma unroll 4
  for (int k4 = 0; k4 < 32; ++k4) {
    float4 xa = ((const float4*)hh)[k4];
    float4 w0 = Wh4[rA + k4];
    float4 w1 = Wh4[rB + k4];
    float4 w2 = Wh4[rC + k4];
    hr += w0.x * xa.x + w0.y * xa.y + w0.z * xa.z + w0.w * xa.w;
    hz += w1.x * xa.x + w1.y * xa.y + w1.z * xa.z + w1.w * xa.w;
    hn += w2.x * xa.x + w2.y * xa.y + w2.z * xa.z + w2.w * xa.w;
  }
  float rg = sigm(gr + hr);
  float zg = sigm(gz + hz);
  float ng = tanhf(gn + rg * hn);
  float hv = (1.0f - zg) * ng + zg * hv0;
  red[j] = hv * hv;
  __syncthreads();
  for (int s = HD / 2; s > 0; s >>= 1) { if (j < s) red[j] += red[j + s]; __syncthreads(); }
  float rn = 1.0f / fmaxf(sqrtf(red[0]), 1e-12f);
  float o = hv * rn;
  h0d[r * HD + j] = o;
  h0d_bf[r * HD + j] = f2bf_rne(o);
}

// ---- edge aggregation via dst-CSR: two rows per wave, interleaved MLP ----
// PASS=1: gather nh_bf + h0_bf; agg = (Σnh + Σh0)*nm; Tbf = bf16(Σh0)
// PASS=2: gather nh_bf only;    agg = (Σnh + T)*nm  (T read sequentially)
template<int PASS>
__global__ __launch_bounds__(256) void k_edge2(
    const unsigned short* __restrict__ nh_bf, const unsigned short* __restrict__ h0_bf,
    const int* __restrict__ offs, const unsigned* __restrict__ se,
    const float* __restrict__ norm, unsigned* __restrict__ Tbf,
    float* __restrict__ agg) {
  int gw = __builtin_amdgcn_readfirstlane((blockIdx.x * blockDim.x + threadIdx.x) >> 6);
  int lane = threadIdx.x & 63;
  if (gw >= NE2) return;
  int rA = gw, rB = gw + NE2;
  int a0 = offs[rA], a1 = offs[rA + 1];
  int b0 = offs[rB], b1 = offs[rB + 1];
  const unsigned* nh4 = (const unsigned*)nh_bf;
  const unsigned* h04 = (const unsigned*)h0_bf;
  float nax = 0.f, nay = 0.f, tax = 0.f, tay = 0.f;
  float nbx = 0.f, nby = 0.f, tbx = 0.f, tby = 0.f;
  int pa = a0, pb = b0;
  for (; pa + 4 <= a1 && pb + 4 <= b1; pa += 4, pb += 4) {
    unsigned e0 = se[pa], e1 = se[pa + 1], e2 = se[pa + 2], e3 = se[pa + 3];
    unsigned f0 = se[pb], f1 = se[pb + 1], f2 = se[pb + 2], f3 = se[pb + 3];
    unsigned ua = nh4[(size_t)(e0 >> 9) * 64 + lane];
    unsigned ub = nh4[(size_t)(e1 >> 9) * 64 + lane];
    unsigned uc = nh4[(size_t)(e2 >> 9) * 64 + lane];
    unsigned ud = nh4[(size_t)(e3 >> 9) * 64 + lane];
    unsigned va = nh4[(size_t)(f0 >> 9) * 64 + lane];
    unsigned vb = nh4[(size_t)(f1 >> 9) * 64 + lane];
    unsigned vc = nh4[(size_t)(f2 >> 9) * 64 + lane];
    unsigned vd = nh4[(size_t)(f3 >> 9) * 64 + lane];
    nax += (bfLO(ua) + bfLO(ub)) + (bfLO(uc) + bfLO(ud));
    nay += (bfHI(ua) + bfHI(ub)) + (bfHI(uc) + bfHI(ud));
    nbx += (bfLO(va) + bfLO(vb)) + (bfLO(vc) + bfLO(vd));
    nby += (bfHI(va) + bfHI(vb)) + (bfHI(vc) + bfHI(vd));
    if (PASS == 1) {
      unsigned ha = h04[(size_t)(e0 & 511u) * 64 + lane];
      unsigned hb = h04[(size_t)(e1 & 511u) * 64 + lane];
      unsigned hc = h04[(size_t)(e2 & 511u) * 64 + lane];
      unsigned hd = h04[(size_t)(e3 & 511u) * 64 + lane];
      unsigned ga = h04[(size_t)(f0 & 511u) * 64 + lane];
      unsigned gb = h04[(size_t)(f1 & 511u) * 64 + lane];
      unsigned gc = h04[(size_t)(f2 & 511u) * 64 + lane];
      unsigned gd = h04[(size_t)(f3 & 511u) * 64 + lane];
      tax += (bfLO(ha) + bfLO(hb)) + (bfLO(hc) + bfLO(hd));
      tay += (bfHI(ha) + bfHI(hb)) + (bfHI(hc) + bfHI(hd));
      tbx += (bfLO(ga) + bfLO(gb)) + (bfLO(gc) + bfLO(gd));
      tby += (bfHI(ga) + bfHI(gb)) + (bfHI(gc) + bfHI(gd));
    }
  }
  for (; pa < a1; ++pa) {
    unsigned e0 = se[pa];
    unsigned ua = nh4[(size_t)(e0 >> 9) * 64 + lane];
    nax += bfLO(ua);
    nay += bfHI(ua);
    if (PASS == 1) {
      unsigned ha = h04[(size_t)(e0 & 511u) * 64 + lane];
      tax += bfLO(ha);
      tay += bfHI(ha);
    }
  }
  for (; pb < b1; ++pb) {
    unsigned f0 = se[pb];
    unsigned va = nh4[(size_t)(f0 >> 9) * 64 + lane];
    nbx += bfLO(va);
    nby += bfHI(va);
    if (PASS == 1) {
      unsigned ga = h04[(size_t)(f0 & 511u) * 64 + lane];
      tbx += bfLO(ga);
      tby += bfHI(ga);
    }
  }
  float nma = norm[rA], nmb = norm[rB];
  if (PASS == 1) {
    Tbf[(size_t)rA * 64 + lane] = packbf(tax, tay);
    Tbf[(size_t)rB * 64 + lane] = packbf(tbx, tby);
    ((float2*)agg)[(size_t)rA * 64 + lane] = make_float2((nax + tax) * nma, (nay + tay) * nma);
    ((float2*)agg)[(size_t)rB * 64 + lane] = make_float2((nbx + tbx) * nmb, (nby + tby) * nmb);
  } else {
    unsigned tva = Tbf[(size_t)rA * 64 + lane];
    unsigned tvb = Tbf[(size_t)rB * 64 + lane];
    ((float2*)agg)[(size_t)rA * 64 + lane] =
        make_float2((nax + bfLO(tva)) * nma, (nay + bfHI(tva)) * nma);
    ((float2*)agg)[(size_t)rB * 64 + lane] =
        make_float2((nbx + bfLO(tvb)) * nmb, (nby + bfHI(tvb)) * nmb);
  }
}

// ---- stage helper: fp32 global rows -> swizzled hi/lo bf16 LDS ----
__device__ __forceinline__ void stage_rows(const float* __restrict__ A, int base, int nrows,
                                           unsigned short* AsH, unsigned short* AsL,
                                           int tid) {
  const float4* A4 = (const float4*)A;
  #pragma unroll
  for (int it = 0; it < 8; ++it) {
    int idx = tid + it * 256;          // 0..2047
    int r = idx >> 5, c4 = idx & 31;
    int c0 = c4 * 4;
    float4 v = make_float4(0.f, 0.f, 0.f, 0.f);
    if (base + r < nrows) v = A4[(size_t)(base + r) * 32 + c4];
    int chunk = (c0 >> 3) ^ (r & 7);
    int p = r * 128 + chunk * 8 + (c0 & 7);
    unsigned short h0 = f2bf_rne(v.x), h1 = f2bf_rne(v.y);
    unsigned short h2 = f2bf_rne(v.z), h3 = f2bf_rne(v.w);
    ushort4 hv; hv.x = h0; hv.y = h1; hv.z = h2; hv.w = h3;
    *(ushort4*)&AsH[p] = hv;
    ushort4 lv;
    lv.x = f2bf_rne(v.x - bf2f(h0)); lv.y = f2bf_rne(v.y - bf2f(h1));
    lv.z = f2bf_rne(v.z - bf2f(h2)); lv.w = f2bf_rne(v.w - bf2f(h3));
    *(ushort4*)&AsL[p] = lv;
  }
}

// ---- MFMA split-bf16 core: acc += As @ Wfrag ----
__device__ __forceinline__ void mfma_128(const unsigned short* AsH, const unsigned short* AsL,
                                         const unsigned short* __restrict__ wHi,
                                         const unsigned short* __restrict__ wLo,
                                         int w, int lane, facc* acc) {
  int lrow = lane & 15;
  int arow = w * 16 + lrow;
  #pragma unroll
  for (int ks = 0; ks < 4; ++ks) {
    int chunk = (ks * 4 + (lane >> 4)) ^ (arow & 7);
    int p = arow * 128 + chunk * 8;
    bfrag aH = *(const bfrag*)&AsH[p];
    bfrag aL = *(const bfrag*)&AsL[p];
    #pragma unroll
    for (int nt = 0; nt < 8; ++nt) {
      int fi = ((nt * 4 + ks) * 64 + lane) * 8;
      bfrag bH = *(const bfrag*)&wHi[fi];
      bfrag bL = *(const bfrag*)&wLo[fi];
      acc[nt] = __builtin_amdgcn_mfma_f32_16x16x32_bf16(aH, bH, acc[nt], 0, 0, 0);
      acc[nt] = __builtin_amdgcn_mfma_f32_16x16x32_bf16(aH, bL, acc[nt], 0, 0, 0);
      acc[nt] = __builtin_amdgcn_mfma_f32_16x16x32_bf16(aL, bH, acc[nt], 0, 0, 0);
    }
  }
}

// ---- layer-1 matmul: agg1 (fp32) -> agg1_bf = bf16(rrelu(agg1 @ W1)) ----
__global__ __launch_bounds__(256) void k_mm1(
    const float* __restrict__ A, unsigned short* __restrict__ Abf,
    const unsigned short* __restrict__ wHi, const unsigned short* __restrict__ wLo,
    int nrows) {
  __shared__ __align__(16) unsigned short AsH[64 * 128];
  __shared__ __align__(16) unsigned short AsL[64 * 128];
  int tid = threadIdx.x;
  int base = blockIdx.x * 64;
  stage_rows(A, base, nrows, AsH, AsL, tid);
  __syncthreads();
  int w = tid >> 6, lane = tid & 63;
  int lrow = lane & 15, lk = lane >> 4;
  facc acc[8];
  #pragma unroll
  for (int nt = 0; nt < 8; ++nt) acc[nt] = (facc){0.f, 0.f, 0.f, 0.f};
  mfma_128(AsH, AsL, wHi, wLo, w, lane, acc);
  #pragma unroll
  for (int nt = 0; nt < 8; ++nt)
    #pragma unroll
    for (int r = 0; r < 4; ++r) {
      int row = base + w * 16 + lk * 4 + r;
      if (row < nrows) Abf[(size_t)row * HD + nt * 16 + lrow] = f2bf_rne(rrelu_f(acc[nt][r]));
    }
}

// ---- FUSED layer-2 matmul + time-gate final ----
__global__ __launch_bounds__(256) void k_mm2_final(
    const float* __restrict__ A, const float* __restrict__ Hin,
    float* __restrict__ Hout, unsigned short* __restrict__ Hout_bf,
    const unsigned short* __restrict__ w2Hi, const unsigned short* __restrict__ w2Lo,
    const unsigned short* __restrict__ wtHi, const unsigned short* __restrict__ wtLo,
    const float* __restrict__ bias, int nrows) {
  __shared__ __align__(16) unsigned short AsH[64 * 128];
  __shared__ __align__(16) unsigned short AsL[64 * 128];
  int tid = threadIdx.x;
  int base = blockIdx.x * 64;
  int w = tid >> 6, lane = tid & 63;
  int lrow = lane & 15, lk = lane >> 4;
  // phase 1: C = rrelu(agg2 @ W2)
  stage_rows(A, base, nrows, AsH, AsL, tid);
  __syncthreads();
  facc acc[8];
  #pragma unroll
  for (int nt = 0; nt < 8; ++nt) acc[nt] = (facc){0.f, 0.f, 0.f, 0.f};
  mfma_128(AsH, AsL, w2Hi, w2Lo, w, lane, acc);
  #pragma unroll
  for (int nt = 0; nt < 8; ++nt)
    #pragma unroll
    for (int r = 0; r < 4; ++r) acc[nt][r] = rrelu_f(acc[nt][r]);
  __syncthreads();   // all LDS reads of phase 1 done before overwrite
  // phase 2: tw-gate matmul on Hin
  stage_rows(Hin, base, nrows, AsH, AsL, tid);
  __syncthreads();
  facc acc2[8];
  #pragma unroll
  for (int nt = 0; nt < 8; ++nt) acc2[nt] = (facc){0.f, 0.f, 0.f, 0.f};
  mfma_128(AsH, AsL, wtHi, wtLo, w, lane, acc2);
  // l2norm of C rows (one wave owns a full row: 16 lanes x 8 nt)
  float ss[4] = {0.f, 0.f, 0.f, 0.f};
  #pragma unroll
  for (int r = 0; r < 4; ++r) {
    #pragma unroll
    for (int nt = 0; nt < 8; ++nt) ss[r] += acc[nt][r] * acc[nt][r];
    #pragma unroll
    for (int o = 1; o < 16; o <<= 1) ss[r] += __shfl_xor(ss[r], o, 64);
    ss[r] = 1.0f / fmaxf(sqrtf(ss[r]), 1e-12f);
  }
  #pragma unroll
  for (int r = 0; r < 4; ++r) {
    int row = base + w * 16 + lk * 4 + r;
    if (row >= nrows) continue;
    #pragma unroll
    for (int nt = 0; nt < 8; ++nt) {
      int col = nt * 16 + lrow;
      float hv = Hin[(size_t)row * HD + col];
      float tw = sigm(acc2[nt][r] + bias[col]);
      float res = tw * (acc[nt][r] * ss[r]) + (1.0f - tw) * hv;
      Hout[(size_t)row * HD + col] = res;
      Hout_bf[(size_t)row * HD + col] = f2bf_rne(res);
    }
  }
}

extern "C" void kernel_launch(void* const* d_in, const int* in_sizes, int n_in,
                              void* d_out, int out_size, void* d_ws, size_t ws_size,
                              hipStream_t stream) {
  const int* src    = (const int*)d_in[0];
  const int* dst    = (const int*)d_in[1];
  const int* etype  = (const int*)d_in[2];
  const int* rte    = (const int*)d_in[3];
  const int* rseg   = (const int*)d_in[4];
  const float* dyn  = (const float*)d_in[5];
  const float* emb_rel = (const float*)d_in[6];
  const float* W_ih = (const float*)d_in[7];
  const float* W_hh = (const float*)d_in[8];
  const float* b_ih = (const float*)d_in[9];
  const float* b_hh = (const float*)d_in[10];
  const float* rgcnW = (const float*)d_in[11];
  const float* tgW  = (const float*)d_in[12];
  const float* tgB  = (const float*)d_in[13];
  float* out = (float*)d_out;
  (void)in_sizes; (void)n_in; (void)out_size; (void)ws_size;

  float* ws = (float*)d_ws;
  size_t off = 0;
  float* agg1    = ws + off; off += (size_t)NENT * HD;
  float* agg2    = ws + off; off += (size_t)NENT * HD;
  float* parts   = ws + off; off += (size_t)RSP * NR2 * HD;
  float* h0a     = ws + off; off += (size_t)NR2 * HD;
  float* h0b     = ws + off; off += (size_t)NR2 * HD;
  float* normv8  = ws + off; off += NTOT;
  float* invc8   = ws + off; off += TS * NR2;
  off = (off + 3) & ~(size_t)3;
  unsigned* Tbf  = (unsigned*)(ws + off); off += (size_t)NENT * 64;
  unsigned short* h_bf    = (unsigned short*)(ws + off); off += (size_t)NENT * HD / 2;
  unsigned short* agg1_bf = (unsigned short*)(ws + off); off += (size_t)NENT * HD / 2;
  unsigned short* h0abf   = (unsigned short*)(ws + off); off += (size_t)NR2 * HD / 2 + 1;
  unsigned short* h0bbf   = (unsigned short*)(ws + off); off += (size_t)NR2 * HD / 2 + 1;
  unsigned short* wf = (unsigned short*)(ws + off);
  unsigned short* w1H = wf;            unsigned short* w1L = wf + 16384;
  unsigned short* w2H = wf + 32768;    unsigned short* w2L = wf + 49152;
  unsigned short* wtH = wf + 65536;    unsigned short* wtL = wf + 81920;
  off += (6 * 16384) / 2;
  unsigned* csr_se8 = (unsigned*)(ws + off); off += (size_t)TS * EPC;
  int* csr_rte8  = (int*)(ws + off);  off += (size_t)TS * MPC;
  int* degE8     = (int*)(ws + off);  off += NTOT;
  int* offsE8    = (int*)(ws + off);  off += NTOT + 2;
  int* curE8     = (int*)(ws + off);  off += NTOT;
  int* bsum      = (int*)(ws + off);  off += NB8;
  int* blkcntR8  = (int*)(ws + off);  off += (size_t)TS * RBLK * NR2;
  int* offsR8    = (int*)(ws + off);  off += TS * NR2 + 2;
  int* totR      = (int*)(ws + off);  off += TS * NR2;

  // ===== hoisted, batched CSR builds for all TS steps (input-only) =====
  hipMemsetAsync(degE8, 0, (size_t)NTOT * sizeof(int), stream);
  k_hist<<<2048, 256, 0, stream>>>(dst, degE8, TS * EPC, EPC, NENT);
  k_scan1<<<NB8, 256, 0, stream>>>(degE8, offsE8, normv8, bsum);
  k_scan2<<<1, 256, 0, stream>>>(bsum);
  k_scan3<<<NB8, 256, 0, stream>>>(offsE8, curE8, bsum);
  k_scatterE<<<1024, 256, 0, stream>>>(src, dst, etype, curE8, csr_se8);
  k_histR2<<<dim3(RBLK, TS), 256, 0, stream>>>(rseg, blkcntR8);
  k_scanR2a<<<(TS * NR2 + 255) / 256, 256, 0, stream>>>(blkcntR8, totR);
  k_scanR2b<<<1, 512, 0, stream>>>(totR, offsR8, invc8);
  k_scanR2c<<<(TS * NR2 * 64 + 255) / 256, 256, 0, stream>>>(blkcntR8, offsR8);
  k_scatterR2<<<dim3(RBLK, TS), 256, 0, stream>>>(rte, rseg, blkcntR8, csr_rte8);
  k_prepW<<<8, 256, 0, stream>>>(rgcnW, w1H, w1L);
  k_prepW<<<8, 256, 0, stream>>>(rgcnW + HD * HD, w2H, w2L);
  k_prepW<<<8, 256, 0, stream>>>(tgW, wtH, wtL);

  // h_init = l2norm(dynamic_emb) -> d_out slot 0 + bf16 shadow
  k_l2rows<<<NENT, HD, 0, stream>>>(dyn, out, h_bf);

  float* h0bufs[2] = {h0a, h0b};
  unsigned short* h0bfbufs[2] = {h0abf, h0bbf};
  for (int t = 0; t < TS; ++t) {
    const float* h = out + (size_t)(t == 0 ? 0 : (t - 1)) * NENT * HD;
    float* hout = out + (size_t)t * NENT * HD;
    const float* h0s = (t == 0) ? emb_rel : h0bufs[(t - 1) & 1];
    float* h0d = h0bufs[t & 1];
    unsigned short* h0d_bf = h0bfbufs[t & 1];

    k_relmean<<<dim3(NR2, RSP), 256, 0, stream>>>(h_bf, offsR8 + t * NR2, csr_rte8, parts);
    k_gru<<<NR2, HD, 0, stream>>>(parts, invc8 + t * NR2, emb_rel, h0s,
                                  W_ih, W_hh, b_ih, b_hh, h0d, h0d_bf);

    k_edge2<1><<<(NE2 * 64 + 255) / 256, 256, 0, stream>>>(
        h_bf, h0d_bf, offsE8 + t * NENT, csr_se8, normv8 + t * NENT, Tbf, agg1);
    k_mm1<<<(NENT + 63) / 64, 256, 0, stream>>>(agg1, agg1_bf, w1H, w1L, NENT);
    k_edge2<2><<<(NE2 * 64 + 255) / 256, 256, 0, stream>>>(
        agg1_bf, (const unsigned short*)nullptr, offsE8 + t * NENT, csr_se8,
        normv8 + t * NENT, Tbf, agg2);
    k_mm2_final<<<(NENT + 63) / 64, 256, 0, stream>>>(agg2, h, hout, h_bf,
                                                      w2H, w2L, wtH, wtL, tgB, NENT);
  }
  hipMemcpyAsync(out + (size_t)TS * NENT * HD, h0bufs[(TS - 1) & 1],
                 (size_t)NR2 * HD * sizeof(float), hipMemcpyDeviceToDevice, stream);
}

// Round 13
// 1538.967 us; speedup vs baseline: 1.0363x; 1.0326x over previous
//
#include <hip/hip_runtime.h>
#include <math.h>

#define NENT 50000
#define NE2 (NENT / 2)
#define NR2 460
#define HD 128
#define TS 8
#define EPC 200000   // edges per step
#define MPC 400000   // r_to_e entries per step
#define RSLOPE 0.22916666666666666f
#define RBLK 128                    // blocks per step for two-level relation CSR build
#define NTOT (TS * NENT)            // 400000 flattened (t, entity)
#define NB8 ((NTOT + 255) / 256)    // 1563 scan blocks
#define SCAN2_PER ((NB8 + 255) / 256)  // 7
#define RSP 8                       // relmean splits

typedef __attribute__((ext_vector_type(8))) short bfrag;   // 8 bf16 (4 VGPR)
typedef __attribute__((ext_vector_type(4))) float facc;    // mfma f32x4 acc

__device__ __forceinline__ float sigm(float x) { return 1.0f / (1.0f + expf(-x)); }
__device__ __forceinline__ float rrelu_f(float x) { return x >= 0.0f ? x : RSLOPE * x; }
__device__ __forceinline__ unsigned short f2bf_rne(float x) {
  unsigned u = __float_as_uint(x);
  unsigned r = (u + 0x7FFFu + ((u >> 16) & 1u)) >> 16;
  return (unsigned short)r;
}
__device__ __forceinline__ float bf2f(unsigned short b) {
  return __uint_as_float(((unsigned)b) << 16);
}
__device__ __forceinline__ float bfLO(unsigned u) { return __uint_as_float(u << 16); }
__device__ __forceinline__ float bfHI(unsigned u) { return __uint_as_float(u & 0xFFFF0000u); }

// ---- row l2 normalize (+ bf16 shadow) ----
__global__ __launch_bounds__(HD) void k_l2rows(const float* __restrict__ in,
                                               float* __restrict__ out,
                                               unsigned short* __restrict__ out_bf) {
  int r = blockIdx.x, j = threadIdx.x;
  __shared__ float red[HD];
  float v = in[(size_t)r * HD + j];
  red[j] = v * v;
  __syncthreads();
  for (int s = HD / 2; s > 0; s >>= 1) { if (j < s) red[j] += red[j + s]; __syncthreads(); }
  float rn = 1.0f / fmaxf(sqrtf(red[0]), 1e-12f);
  float o = v * rn;
  out[(size_t)r * HD + j] = o;
  out_bf[(size_t)r * HD + j] = f2bf_rne(o);
}

// ---- batched histogram ----
__global__ void k_hist(const int* __restrict__ idx, int* __restrict__ cnt,
                       int n, int per_t, int stride) {
  int i = blockIdx.x * blockDim.x + threadIdx.x;
  int gs = gridDim.x * blockDim.x;
  for (; i < n; i += gs) atomicAdd(&cnt[(i / per_t) * stride + idx[i]], 1);
}

// ==== batched two-level relation CSR build ====
__global__ __launch_bounds__(256) void k_histR2(const int* __restrict__ rseg,
                                                int* __restrict__ blkcnt) {
  __shared__ int h[NR2];
  int b = blockIdx.x, t = blockIdx.y, tid = threadIdx.x;
  for (int i = tid; i < NR2; i += 256) h[i] = 0;
  __syncthreads();
  const int* rs = rseg + (size_t)t * MPC;
  int chunk = (MPC + RBLK - 1) / RBLK;
  int m0 = b * chunk, m1 = min(MPC, m0 + chunk);
  for (int m = m0 + tid; m < m1; m += 256) atomicAdd(&h[rs[m]], 1);
  __syncthreads();
  for (int i = tid; i < NR2; i += 256) blkcnt[((size_t)(t * RBLK + b)) * NR2 + i] = h[i];
}

__global__ __launch_bounds__(256) void k_scanR2a(const int* __restrict__ blkcnt,
                                                 int* __restrict__ tot) {
  int idx = blockIdx.x * 256 + threadIdx.x;
  if (idx >= TS * NR2) return;
  int t = idx / NR2, r = idx - t * NR2;
  int s = 0;
  for (int b = 0; b < RBLK; ++b) s += blkcnt[((size_t)(t * RBLK + b)) * NR2 + r];
  tot[idx] = s;
}

__global__ __launch_bounds__(512) void k_scanR2b(const int* __restrict__ tot,
    int* __restrict__ offsR, float* __restrict__ invc) {
  __shared__ int s[TS * NR2];
  int tid = threadIdx.x;
  for (int i = tid; i < TS * NR2; i += 512) s[i] = tot[i];
  __syncthreads();
  if (tid < TS) {
    int acc = tid * MPC;
    for (int r = 0; r < NR2; ++r) { int c = s[tid * NR2 + r]; s[tid * NR2 + r] = acc; acc += c; }
  }
  __syncthreads();
  for (int i = tid; i < TS * NR2; i += 512) {
    offsR[i] = s[i];
    int c = tot[i];
    invc[i] = c > 0 ? 1.0f / (float)c : 0.0f;
  }
  if (tid == 0) offsR[TS * NR2] = TS * MPC;
}

__global__ __launch_bounds__(256) void k_scanR2c(int* __restrict__ blkcnt,
                                                 const int* __restrict__ offsR) {
  int gw = (blockIdx.x * blockDim.x + threadIdx.x) >> 6;
  int lane = threadIdx.x & 63;
  if (gw >= TS * NR2) return;
  int t = gw / NR2, r = gw - t * NR2;
  size_t i0 = ((size_t)(t * RBLK + lane * 2)) * NR2 + r;
  size_t i1 = ((size_t)(t * RBLK + lane * 2 + 1)) * NR2 + r;
  int v0 = blkcnt[i0], v1 = blkcnt[i1];
  int s = v0 + v1;
  int sc = s;
  #pragma unroll
  for (int o = 1; o < 64; o <<= 1) {
    int x = __shfl_up(sc, o, 64);
    if (lane >= o) sc += x;
  }
  int basev = offsR[gw] + (sc - s);
  blkcnt[i0] = basev;
  blkcnt[i1] = basev + v0;
}

__global__ __launch_bounds__(256) void k_scatterR2(const int* __restrict__ rte,
    const int* __restrict__ rseg, const int* __restrict__ blkbase,
    int* __restrict__ out) {
  __shared__ int cur[NR2];
  int b = blockIdx.x, t = blockIdx.y, tid = threadIdx.x;
  for (int i = tid; i < NR2; i += 256) cur[i] = blkbase[((size_t)(t * RBLK + b)) * NR2 + i];
  __syncthreads();
  const int* rs = rseg + (size_t)t * MPC;
  const int* re = rte + (size_t)t * MPC;
  int chunk = (MPC + RBLK - 1) / RBLK;
  int m0 = b * chunk, m1 = min(MPC, m0 + chunk);
  for (int m = m0 + tid; m < m1; m += 256) {
    int r = rs[m];
    int p = atomicAdd(&cur[r], 1);
    out[p] = re[m];
  }
}

// ---- flat 3-phase exclusive scan over TS*NENT degrees ----
__global__ __launch_bounds__(256) void k_scan1(const int* __restrict__ deg,
    int* __restrict__ offs, float* __restrict__ normv, int* __restrict__ bsum) {
  __shared__ int sd[256];
  int b = blockIdx.x, tid = threadIdx.x;
  int i = b * 256 + tid;
  int v = (i < NTOT) ? deg[i] : 0;
  sd[tid] = v;
  __syncthreads();
  for (int o = 1; o < 256; o <<= 1) {
    int x = (tid >= o) ? sd[tid - o] : 0;
    __syncthreads();
    sd[tid] += x;
    __syncthreads();
  }
  if (i < NTOT) {
    offs[i] = sd[tid] - v;
    normv[i] = v > 0 ? 1.0f / (float)v : 0.0f;
  }
  if (tid == 255) bsum[b] = sd[255];
}

__global__ __launch_bounds__(256) void k_scan2(int* __restrict__ bsum) {
  __shared__ int part[256];
  int tid = threadIdx.x;
  int base = tid * SCAN2_PER;
  int local[SCAN2_PER];
  int s = 0;
  #pragma unroll
  for (int k = 0; k < SCAN2_PER; ++k) {
    int v = (base + k < NB8) ? bsum[base + k] : 0;
    local[k] = s;
    s += v;
  }
  part[tid] = s;
  __syncthreads();
  for (int o = 1; o < 256; o <<= 1) {
    int x = (tid >= o) ? part[tid - o] : 0;
    __syncthreads();
    part[tid] += x;
    __syncthreads();
  }
  int pre = (tid > 0) ? part[tid - 1] : 0;
  #pragma unroll
  for (int k = 0; k < SCAN2_PER; ++k)
    if (base + k < NB8) bsum[base + k] = pre + local[k];
}

__global__ __launch_bounds__(256) void k_scan3(int* __restrict__ offs, int* __restrict__ cur,
                                               const int* __restrict__ bsum) {
  int b = blockIdx.x;
  int i = b * 256 + threadIdx.x;
  if (i < NTOT) {
    int o = offs[i] + bsum[b];
    offs[i] = o;
    cur[i] = o;
  }
  if (b == 0 && threadIdx.x == 0) offs[NTOT] = TS * EPC;
}

// packed edge payload: (src << 9) | etype ; t-outer loop keeps write window L2-resident
__global__ void k_scatterE(const int* __restrict__ src, const int* __restrict__ dst,
                           const int* __restrict__ ety, int* __restrict__ cur,
                           unsigned* __restrict__ se) {
  int tid0 = blockIdx.x * blockDim.x + threadIdx.x;
  int gs = gridDim.x * blockDim.x;
  for (int t = 0; t < TS; ++t) {
    const int* s = src + (size_t)t * EPC;
    const int* d = dst + (size_t)t * EPC;
    const int* e = ety + (size_t)t * EPC;
    int* ct = cur + t * NENT;
    for (int i = tid0; i < EPC; i += gs) {
      int dd = d[i];
      int p = atomicAdd(&ct[dd], 1);
      se[p] = ((unsigned)s[i] << 9) | (unsigned)e[i];
    }
  }
}

// ---- W -> fragment-layout bf16 hi/lo (B-operand of mfma_f32_16x16x32_bf16) ----
__global__ __launch_bounds__(256) void k_prepW(const float* __restrict__ W,
    unsigned short* __restrict__ hi, unsigned short* __restrict__ lo) {
  int t = blockIdx.x * 256 + threadIdx.x;   // 0..2047
  int nt = t >> 8, ks = (t >> 6) & 3, lane = t & 63;
  int n = nt * 16 + (lane & 15);
  int k0 = ks * 32 + ((lane >> 4) << 3);
  #pragma unroll
  for (int j = 0; j < 8; ++j) {
    float v = W[(k0 + j) * HD + n];
    unsigned short h = f2bf_rne(v);
    hi[t * 8 + j] = h;
    lo[t * 8 + j] = f2bf_rne(v - bf2f(h));
  }
}

// ---- relation partial sums via CSR gather (bf16 rows, 4-deep MLP) ----
__global__ __launch_bounds__(256) void k_relmean(const unsigned short* __restrict__ h_bf,
    const int* __restrict__ offs, const int* __restrict__ rte_csr,
    float* __restrict__ partials) {
  int rel = blockIdx.x, sp = blockIdx.y;
  int o0 = offs[rel], o1 = offs[rel + 1];
  int n = o1 - o0;
  int w = __builtin_amdgcn_readfirstlane(threadIdx.x >> 6);
  int lane = threadIdx.x & 63;
  int s0 = o0 + ((n * sp) >> 3);
  int s1 = o0 + ((n * (sp + 1)) >> 3);
  const unsigned* h4 = (const unsigned*)h_bf;   // 2 bf16 per u32; row = 64 u32
  float sx = 0.f, sy = 0.f;
  int p = s0 + w;
  for (; p + 12 < s1; p += 16) {   // 4-deep MLP, wave-stride 4
    int i0 = rte_csr[p];
    int i1 = rte_csr[p + 4];
    int i2 = rte_csr[p + 8];
    int i3 = rte_csr[p + 12];
    unsigned u0 = h4[(size_t)i0 * 64 + lane];
    unsigned u1 = h4[(size_t)i1 * 64 + lane];
    unsigned u2 = h4[(size_t)i2 * 64 + lane];
    unsigned u3 = h4[(size_t)i3 * 64 + lane];
    sx += (bfLO(u0) + bfLO(u1)) + (bfLO(u2) + bfLO(u3));
    sy += (bfHI(u0) + bfHI(u1)) + (bfHI(u2) + bfHI(u3));
  }
  for (; p < s1; p += 4) {
    unsigned u0 = h4[(size_t)rte_csr[p] * 64 + lane];
    sx += bfLO(u0);
    sy += bfHI(u0);
  }
  __shared__ float red[4][HD];
  red[w][lane * 2] = sx;
  red[w][lane * 2 + 1] = sy;
  __syncthreads();
  if (threadIdx.x < HD) {
    int j = threadIdx.x;
    float t = red[0][j] + red[1][j] + red[2][j] + red[3][j];
    partials[((size_t)sp * NR2 + rel) * HD + j] = t;
  }
}

// ---- GRU cell + l2norm for 460 relation rows ----
__global__ __launch_bounds__(HD) void k_gru(
    const float* __restrict__ partials, const float* __restrict__ invcnt,
    const float* __restrict__ emb_rel, const float* __restrict__ h0s,
    const float* __restrict__ Wih, const float* __restrict__ Whh,
    const float* __restrict__ bih, const float* __restrict__ bhh,
    float* __restrict__ h0d) {
  int r = blockIdx.x, j = threadIdx.x;
  __shared__ __align__(16) float xr[2 * HD];
  __shared__ __align__(16) float hh[HD];
  __shared__ float red[HD];
  float inv = invcnt[r];
  xr[j] = emb_rel[r * HD + j];
  float xm = 0.f;
  #pragma unroll
  for (int sp = 0; sp < RSP; ++sp) xm += partials[((size_t)sp * NR2 + r) * HD + j];
  xr[HD + j] = xm * inv;
  float hv0 = h0s[r * HD + j];
  hh[j] = hv0;
  __syncthreads();
  float gr = bih[j], gz = bih[HD + j], gn = bih[2 * HD + j];
  const float4* W4 = (const float4*)Wih;
  int rowA = j * 64, rowB = (j + HD) * 64, rowC = (j + 2 * HD) * 64;
  #pragma unroll 4
  for (int k4 = 0; k4 < 64; ++k4) {
    float4 xa = ((const float4*)xr)[k4];
    float4 w0 = W4[rowA + k4];
    float4 w1 = W4[rowB + k4];
    float4 w2 = W4[rowC + k4];
    gr += w0.x * xa.x + w0.y * xa.y + w0.z * xa.z + w0.w * xa.w;
    gz += w1.x * xa.x + w1.y * xa.y + w1.z * xa.z + w1.w * xa.w;
    gn += w2.x * xa.x + w2.y * xa.y + w2.z * xa.z + w2.w * xa.w;
  }
  float hr = bhh[j], hz = bhh[HD + j], hn = bhh[2 * HD + j];
  const float4* Wh4 = (const float4*)Whh;
  int rA = j * 32, rB = (j + HD) * 32, rC = (j + 2 * HD) * 32;
  #pragma unroll 4
  for (int k4 = 0; k4 < 32; ++k4) {
    float4 xa = ((const float4*)hh)[k4];
    float4 w0 = Wh4[rA + k4];
    float4 w1 = Wh4[rB + k4];
    float4 w2 = Wh4[rC + k4];
    hr += w0.x * xa.x + w0.y * xa.y + w0.z * xa.z + w0.w * xa.w;
    hz += w1.x * xa.x + w1.y * xa.y + w1.z * xa.z + w1.w * xa.w;
    hn += w2.x * xa.x + w2.y * xa.y + w2.z * xa.z + w2.w * xa.w;
  }
  float rg = sigm(gr + hr);
  float zg = sigm(gz + hz);
  float ng = tanhf(gn + rg * hn);
  float hv = (1.0f - zg) * ng + zg * hv0;
  red[j] = hv * hv;
  __syncthreads();
  for (int s = HD / 2; s > 0; s >>= 1) { if (j < s) red[j] += red[j + s]; __syncthreads(); }
  float rn = 1.0f / fmaxf(sqrtf(red[0]), 1e-12f);
  h0d[r * HD + j] = hv * rn;
}

// ---- edge aggregation via dst-CSR: TWO rows per wave, interleaved 4+4 MLP ----
__global__ __launch_bounds__(256) void k_edge_csr(
    const unsigned short* __restrict__ nh_bf, const float* __restrict__ h0,
    const int* __restrict__ offs, const unsigned* __restrict__ se,
    const float* __restrict__ norm, float* __restrict__ agg) {
  int gw = __builtin_amdgcn_readfirstlane((blockIdx.x * blockDim.x + threadIdx.x) >> 6);
  int lane = threadIdx.x & 63;
  if (gw >= NE2) return;
  int rA = gw, rB = gw + NE2;
  int a0 = offs[rA], a1 = offs[rA + 1];
  int b0 = offs[rB], b1 = offs[rB + 1];
  const unsigned* nh4 = (const unsigned*)nh_bf;
  const float2* h02 = (const float2*)h0;
  float sxa = 0.f, sya = 0.f, sxb = 0.f, syb = 0.f;
  int pa = a0, pb = b0;
  // joint loop: 8 edges (16 gathers) outstanding
  for (; pa + 4 <= a1 && pb + 4 <= b1; pa += 4, pb += 4) {
    unsigned e0 = se[pa], e1 = se[pa + 1], e2 = se[pa + 2], e3 = se[pa + 3];
    unsigned f0 = se[pb], f1 = se[pb + 1], f2 = se[pb + 2], f3 = se[pb + 3];
    unsigned ua = nh4[(size_t)(e0 >> 9) * 64 + lane];
    unsigned ub = nh4[(size_t)(e1 >> 9) * 64 + lane];
    unsigned uc = nh4[(size_t)(e2 >> 9) * 64 + lane];
    unsigned ud = nh4[(size_t)(e3 >> 9) * 64 + lane];
    unsigned va = nh4[(size_t)(f0 >> 9) * 64 + lane];
    unsigned vb = nh4[(size_t)(f1 >> 9) * 64 + lane];
    unsigned vc = nh4[(size_t)(f2 >> 9) * 64 + lane];
    unsigned vd = nh4[(size_t)(f3 >> 9) * 64 + lane];
    float2 ra = h02[(size_t)(e0 & 511u) * 64 + lane];
    float2 rb = h02[(size_t)(e1 & 511u) * 64 + lane];
    float2 rc = h02[(size_t)(e2 & 511u) * 64 + lane];
    float2 rd = h02[(size_t)(e3 & 511u) * 64 + lane];
    float2 qa = h02[(size_t)(f0 & 511u) * 64 + lane];
    float2 qb = h02[(size_t)(f1 & 511u) * 64 + lane];
    float2 qc = h02[(size_t)(f2 & 511u) * 64 + lane];
    float2 qd = h02[(size_t)(f3 & 511u) * 64 + lane];
    sxa += ((bfLO(ua) + ra.x) + (bfLO(ub) + rb.x)) +
           ((bfLO(uc) + rc.x) + (bfLO(ud) + rd.x));
    sya += ((bfHI(ua) + ra.y) + (bfHI(ub) + rb.y)) +
           ((bfHI(uc) + rc.y) + (bfHI(ud) + rd.y));
    sxb += ((bfLO(va) + qa.x) + (bfLO(vb) + qb.x)) +
           ((bfLO(vc) + qc.x) + (bfLO(vd) + qd.x));
    syb += ((bfHI(va) + qa.y) + (bfHI(vb) + qb.y)) +
           ((bfHI(vc) + qc.y) + (bfHI(vd) + qd.y));
  }
  // drain A
  for (; pa + 4 <= a1; pa += 4) {
    unsigned e0 = se[pa], e1 = se[pa + 1], e2 = se[pa + 2], e3 = se[pa + 3];
    unsigned ua = nh4[(size_t)(e0 >> 9) * 64 + lane];
    unsigned ub = nh4[(size_t)(e1 >> 9) * 64 + lane];
    unsigned uc = nh4[(size_t)(e2 >> 9) * 64 + lane];
    unsigned ud = nh4[(size_t)(e3 >> 9) * 64 + lane];
    float2 ra = h02[(size_t)(e0 & 511u) * 64 + lane];
    float2 rb = h02[(size_t)(e1 & 511u) * 64 + lane];
    float2 rc = h02[(size_t)(e2 & 511u) * 64 + lane];
    float2 rd = h02[(size_t)(e3 & 511u) * 64 + lane];
    sxa += ((bfLO(ua) + ra.x) + (bfLO(ub) + rb.x)) +
           ((bfLO(uc) + rc.x) + (bfLO(ud) + rd.x));
    sya += ((bfHI(ua) + ra.y) + (bfHI(ub) + rb.y)) +
           ((bfHI(uc) + rc.y) + (bfHI(ud) + rd.y));
  }
  if (pa + 2 <= a1) {
    unsigned e0 = se[pa], e1 = se[pa + 1];
    unsigned ua = nh4[(size_t)(e0 >> 9) * 64 + lane];
    unsigned ub = nh4[(size_t)(e1 >> 9) * 64 + lane];
    float2 ra = h02[(size_t)(e0 & 511u) * 64 + lane];
    float2 rb = h02[(size_t)(e1 & 511u) * 64 + lane];
    sxa += (bfLO(ua) + ra.x) + (bfLO(ub) + rb.x);
    sya += (bfHI(ua) + ra.y) + (bfHI(ub) + rb.y);
    pa += 2;
  }
  if (pa < a1) {
    unsigned e0 = se[pa];
    unsigned ua = nh4[(size_t)(e0 >> 9) * 64 + lane];
    float2 ra = h02[(size_t)(e0 & 511u) * 64 + lane];
    sxa += bfLO(ua) + ra.x;
    sya += bfHI(ua) + ra.y;
  }
  // drain B
  for (; pb + 4 <= b1; pb += 4) {
    unsigned f0 = se[pb], f1 = se[pb + 1], f2 = se[pb + 2], f3 = se[pb + 3];
    unsigned va = nh4[(size_t)(f0 >> 9) * 64 + lane];
    unsigned vb = nh4[(size_t)(f1 >> 9) * 64 + lane];
    unsigned vc = nh4[(size_t)(f2 >> 9) * 64 + lane];
    unsigned vd = nh4[(size_t)(f3 >> 9) * 64 + lane];
    float2 qa = h02[(size_t)(f0 & 511u) * 64 + lane];
    float2 qb = h02[(size_t)(f1 & 511u) * 64 + lane];
    float2 qc = h02[(size_t)(f2 & 511u) * 64 + lane];
    float2 qd = h02[(size_t)(f3 & 511u) * 64 + lane];
    sxb += ((bfLO(va) + qa.x) + (bfLO(vb) + qb.x)) +
           ((bfLO(vc) + qc.x) + (bfLO(vd) + qd.x));
    syb += ((bfHI(va) + qa.y) + (bfHI(vb) + qb.y)) +
           ((bfHI(vc) + qc.y) + (bfHI(vd) + qd.y));
  }
  if (pb + 2 <= b1) {
    unsigned f0 = se[pb], f1 = se[pb + 1];
    unsigned va = nh4[(size_t)(f0 >> 9) * 64 + lane];
    unsigned vb = nh4[(size_t)(f1 >> 9) * 64 + lane];
    float2 qa = h02[(size_t)(f0 & 511u) * 64 + lane];
    float2 qb = h02[(size_t)(f1 & 511u) * 64 + lane];
    sxb += (bfLO(va) + qa.x) + (bfLO(vb) + qb.x);
    syb += (bfHI(va) + qa.y) + (bfHI(vb) + qb.y);
    pb += 2;
  }
  if (pb < b1) {
    unsigned f0 = se[pb];
    unsigned va = nh4[(size_t)(f0 >> 9) * 64 + lane];
    float2 qa = h02[(size_t)(f0 & 511u) * 64 + lane];
    sxb += bfLO(va) + qa.x;
    syb += bfHI(va) + qa.y;
  }
  float nma = norm[rA], nmb = norm[rB];
  ((float2*)agg)[(size_t)rA * 64 + lane] = make_float2(sxa * nma, sya * nma);
  ((float2*)agg)[(size_t)rB * 64 + lane] = make_float2(sxb * nmb, syb * nmb);
}

// ---- stage helper: fp32 global rows -> swizzled hi/lo bf16 LDS ----
__device__ __forceinline__ void stage_rows(const float* __restrict__ A, int base, int nrows,
                                           unsigned short* AsH, unsigned short* AsL,
                                           int tid) {
  const float4* A4 = (const float4*)A;
  #pragma unroll
  for (int it = 0; it < 8; ++it) {
    int idx = tid + it * 256;          // 0..2047
    int r = idx >> 5, c4 = idx & 31;
    int c0 = c4 * 4;
    float4 v = make_float4(0.f, 0.f, 0.f, 0.f);
    if (base + r < nrows) v = A4[(size_t)(base + r) * 32 + c4];
    int chunk = (c0 >> 3) ^ (r & 7);
    int p = r * 128 + chunk * 8 + (c0 & 7);
    unsigned short h0 = f2bf_rne(v.x), h1 = f2bf_rne(v.y);
    unsigned short h2 = f2bf_rne(v.z), h3 = f2bf_rne(v.w);
    ushort4 hv; hv.x = h0; hv.y = h1; hv.z = h2; hv.w = h3;
    *(ushort4*)&AsH[p] = hv;
    ushort4 lv;
    lv.x = f2bf_rne(v.x - bf2f(h0)); lv.y = f2bf_rne(v.y - bf2f(h1));
    lv.z = f2bf_rne(v.z - bf2f(h2)); lv.w = f2bf_rne(v.w - bf2f(h3));
    *(ushort4*)&AsL[p] = lv;
  }
}

// ---- MFMA split-bf16 core: acc += As @ Wfrag ----
__device__ __forceinline__ void mfma_128(const unsigned short* AsH, const unsigned short* AsL,
                                         const unsigned short* __restrict__ wHi,
                                         const unsigned short* __restrict__ wLo,
                                         int w, int lane, facc* acc) {
  int lrow = lane & 15;
  int arow = w * 16 + lrow;
  #pragma unroll
  for (int ks = 0; ks < 4; ++ks) {
    int chunk = (ks * 4 + (lane >> 4)) ^ (arow & 7);
    int p = arow * 128 + chunk * 8;
    bfrag aH = *(const bfrag*)&AsH[p];
    bfrag aL = *(const bfrag*)&AsL[p];
    #pragma unroll
    for (int nt = 0; nt < 8; ++nt) {
      int fi = ((nt * 4 + ks) * 64 + lane) * 8;
      bfrag bH = *(const bfrag*)&wHi[fi];
      bfrag bL = *(const bfrag*)&wLo[fi];
      acc[nt] = __builtin_amdgcn_mfma_f32_16x16x32_bf16(aH, bH, acc[nt], 0, 0, 0);
      acc[nt] = __builtin_amdgcn_mfma_f32_16x16x32_bf16(aH, bL, acc[nt], 0, 0, 0);
      acc[nt] = __builtin_amdgcn_mfma_f32_16x16x32_bf16(aL, bH, acc[nt], 0, 0, 0);
    }
  }
}

// ---- layer-1 matmul: agg1 (fp32) -> agg1_bf = bf16(rrelu(agg1 @ W1)) ----
__global__ __launch_bounds__(256) void k_mm1(
    const float* __restrict__ A, unsigned short* __restrict__ Abf,
    const unsigned short* __restrict__ wHi, const unsigned short* __restrict__ wLo,
    int nrows) {
  __shared__ __align__(16) unsigned short AsH[64 * 128];
  __shared__ __align__(16) unsigned short AsL[64 * 128];
  int tid = threadIdx.x;
  int base = blockIdx.x * 64;
  stage_rows(A, base, nrows, AsH, AsL, tid);
  __syncthreads();
  int w = tid >> 6, lane = tid & 63;
  int lrow = lane & 15, lk = lane >> 4;
  facc acc[8];
  #pragma unroll
  for (int nt = 0; nt < 8; ++nt) acc[nt] = (facc){0.f, 0.f, 0.f, 0.f};
  mfma_128(AsH, AsL, wHi, wLo, w, lane, acc);
  #pragma unroll
  for (int nt = 0; nt < 8; ++nt)
    #pragma unroll
    for (int r = 0; r < 4; ++r) {
      int row = base + w * 16 + lk * 4 + r;
      if (row < nrows) Abf[(size_t)row * HD + nt * 16 + lrow] = f2bf_rne(rrelu_f(acc[nt][r]));
    }
}

// ---- FUSED layer-2 matmul + time-gate final ----
__global__ __launch_bounds__(256) void k_mm2_final(
    const float* __restrict__ A, const float* __restrict__ Hin,
    float* __restrict__ Hout, unsigned short* __restrict__ Hout_bf,
    const unsigned short* __restrict__ w2Hi, const unsigned short* __restrict__ w2Lo,
    const unsigned short* __restrict__ wtHi, const unsigned short* __restrict__ wtLo,
    const float* __restrict__ bias, int nrows) {
  __shared__ __align__(16) unsigned short AsH[64 * 128];
  __shared__ __align__(16) unsigned short AsL[64 * 128];
  int tid = threadIdx.x;
  int base = blockIdx.x * 64;
  int w = tid >> 6, lane = tid & 63;
  int lrow = lane & 15, lk = lane >> 4;
  // phase 1: C = rrelu(agg2 @ W2)
  stage_rows(A, base, nrows, AsH, AsL, tid);
  __syncthreads();
  facc acc[8];
  #pragma unroll
  for (int nt = 0; nt < 8; ++nt) acc[nt] = (facc){0.f, 0.f, 0.f, 0.f};
  mfma_128(AsH, AsL, w2Hi, w2Lo, w, lane, acc);
  #pragma unroll
  for (int nt = 0; nt < 8; ++nt)
    #pragma unroll
    for (int r = 0; r < 4; ++r) acc[nt][r] = rrelu_f(acc[nt][r]);
  __syncthreads();   // all LDS reads of phase 1 done before overwrite
  // phase 2: tw-gate matmul on Hin
  stage_rows(Hin, base, nrows, AsH, AsL, tid);
  __syncthreads();
  facc acc2[8];
  #pragma unroll
  for (int nt = 0; nt < 8; ++nt) acc2[nt] = (facc){0.f, 0.f, 0.f, 0.f};
  mfma_128(AsH, AsL, wtHi, wtLo, w, lane, acc2);
  // l2norm of C rows (one wave owns a full row: 16 lanes x 8 nt)
  float ss[4] = {0.f, 0.f, 0.f, 0.f};
  #pragma unroll
  for (int r = 0; r < 4; ++r) {
    #pragma unroll
    for (int nt = 0; nt < 8; ++nt) ss[r] += acc[nt][r] * acc[nt][r];
    #pragma unroll
    for (int o = 1; o < 16; o <<= 1) ss[r] += __shfl_xor(ss[r], o, 64);
    ss[r] = 1.0f / fmaxf(sqrtf(ss[r]), 1e-12f);
  }
  #pragma unroll
  for (int r = 0; r < 4; ++r) {
    int row = base + w * 16 + lk * 4 + r;
    if (row >= nrows) continue;
    #pragma unroll
    for (int nt = 0; nt < 8; ++nt) {
      int col = nt * 16 + lrow;
      float hv = Hin[(size_t)row * HD + col];
      float tw = sigm(acc2[nt][r] + bias[col]);
      float res = tw * (acc[nt][r] * ss[r]) + (1.0f - tw) * hv;
      Hout[(size_t)row * HD + col] = res;
      Hout_bf[(size_t)row * HD + col] = f2bf_rne(res);
    }
  }
}

extern "C" void kernel_launch(void* const* d_in, const int* in_sizes, int n_in,
                              void* d_out, int out_size, void* d_ws, size_t ws_size,
                              hipStream_t stream) {
  const int* src    = (const int*)d_in[0];
  const int* dst    = (const int*)d_in[1];
  const int* etype  = (const int*)d_in[2];
  const int* rte    = (const int*)d_in[3];
  const int* rseg   = (const int*)d_in[4];
  const float* dyn  = (const float*)d_in[5];
  const float* emb_rel = (const float*)d_in[6];
  const float* W_ih = (const float*)d_in[7];
  const float* W_hh = (const float*)d_in[8];
  const float* b_ih = (const float*)d_in[9];
  const float* b_hh = (const float*)d_in[10];
  const float* rgcnW = (const float*)d_in[11];
  const float* tgW  = (const float*)d_in[12];
  const float* tgB  = (const float*)d_in[13];
  float* out = (float*)d_out;
  (void)in_sizes; (void)n_in; (void)out_size; (void)ws_size;

  float* ws = (float*)d_ws;
  size_t off = 0;
  float* agg1    = ws + off; off += (size_t)NENT * HD;
  float* agg2    = ws + off; off += (size_t)NENT * HD;
  float* parts   = ws + off; off += (size_t)RSP * NR2 * HD;
  float* h0a     = ws + off; off += (size_t)NR2 * HD;
  float* h0b     = ws + off; off += (size_t)NR2 * HD;
  float* normv8  = ws + off; off += NTOT;
  float* invc8   = ws + off; off += TS * NR2;
  off = (off + 3) & ~(size_t)3;
  unsigned short* h_bf    = (unsigned short*)(ws + off); off += (size_t)NENT * HD / 2;
  unsigned short* agg1_bf = (unsigned short*)(ws + off); off += (size_t)NENT * HD / 2;
  unsigned short* wf = (unsigned short*)(ws + off);
  unsigned short* w1H = wf;            unsigned short* w1L = wf + 16384;
  unsigned short* w2H = wf + 32768;    unsigned short* w2L = wf + 49152;
  unsigned short* wtH = wf + 65536;    unsigned short* wtL = wf + 81920;
  off += (6 * 16384) / 2;
  unsigned* csr_se8 = (unsigned*)(ws + off); off += (size_t)TS * EPC;
  int* csr_rte8  = (int*)(ws + off);  off += (size_t)TS * MPC;
  int* degE8     = (int*)(ws + off);  off += NTOT;
  int* offsE8    = (int*)(ws + off);  off += NTOT + 2;
  int* curE8     = (int*)(ws + off);  off += NTOT;
  int* bsum      = (int*)(ws + off);  off += NB8;
  int* blkcntR8  = (int*)(ws + off);  off += (size_t)TS * RBLK * NR2;
  int* offsR8    = (int*)(ws + off);  off += TS * NR2 + 2;
  int* totR      = (int*)(ws + off);  off += TS * NR2;

  // ===== hoisted, batched CSR builds for all TS steps (input-only) =====
  hipMemsetAsync(degE8, 0, (size_t)NTOT * sizeof(int), stream);
  k_hist<<<2048, 256, 0, stream>>>(dst, degE8, TS * EPC, EPC, NENT);
  k_scan1<<<NB8, 256, 0, stream>>>(degE8, offsE8, normv8, bsum);
  k_scan2<<<1, 256, 0, stream>>>(bsum);
  k_scan3<<<NB8, 256, 0, stream>>>(offsE8, curE8, bsum);
  k_scatterE<<<1024, 256, 0, stream>>>(src, dst, etype, curE8, csr_se8);
  k_histR2<<<dim3(RBLK, TS), 256, 0, stream>>>(rseg, blkcntR8);
  k_scanR2a<<<(TS * NR2 + 255) / 256, 256, 0, stream>>>(blkcntR8, totR);
  k_scanR2b<<<1, 512, 0, stream>>>(totR, offsR8, invc8);
  k_scanR2c<<<(TS * NR2 * 64 + 255) / 256, 256, 0, stream>>>(blkcntR8, offsR8);
  k_scatterR2<<<dim3(RBLK, TS), 256, 0, stream>>>(rte, rseg, blkcntR8, csr_rte8);
  k_prepW<<<8, 256, 0, stream>>>(rgcnW, w1H, w1L);
  k_prepW<<<8, 256, 0, stream>>>(rgcnW + HD * HD, w2H, w2L);
  k_prepW<<<8, 256, 0, stream>>>(tgW, wtH, wtL);

  // h_init = l2norm(dynamic_emb) -> d_out slot 0 + bf16 shadow
  k_l2rows<<<NENT, HD, 0, stream>>>(dyn, out, h_bf);

  float* h0bufs[2] = {h0a, h0b};
  for (int t = 0; t < TS; ++t) {
    const float* h = out + (size_t)(t == 0 ? 0 : (t - 1)) * NENT * HD;
    float* hout = out + (size_t)t * NENT * HD;
    const float* h0s = (t == 0) ? emb_rel : h0bufs[(t - 1) & 1];
    float* h0d = h0bufs[t & 1];

    k_relmean<<<dim3(NR2, RSP), 256, 0, stream>>>(h_bf, offsR8 + t * NR2, csr_rte8, parts);
    k_gru<<<NR2, HD, 0, stream>>>(parts, invc8 + t * NR2, emb_rel, h0s,
                                  W_ih, W_hh, b_ih, b_hh, h0d);

    k_edge_csr<<<(NE2 * 64 + 255) / 256, 256, 0, stream>>>(
        h_bf, h0d, offsE8 + t * NENT, csr_se8, normv8 + t * NENT, agg1);
    k_mm1<<<(NENT + 63) / 64, 256, 0, stream>>>(agg1, agg1_bf, w1H, w1L, NENT);
    k_edge_csr<<<(NE2 * 64 + 255) / 256, 256, 0, stream>>>(
        agg1_bf, h0d, offsE8 + t * NENT, csr_se8, normv8 + t * NENT, agg2);
    k_mm2_final<<<(NENT + 63) / 64, 256, 0, stream>>>(agg2, h, hout, h_bf,
                                                      w2H, w2L, wtH, wtL, tgB, NENT);
  }
  hipMemcpyAsync(out + (size_t)TS * NENT * HD, h0bufs[(TS - 1) & 1],
                 (size_t)NR2 * HD * sizeof(float), hipMemcpyDeviceToDevice, stream);
}